// Round 14
// baseline (276.543 us; speedup 1.0000x reference)
//
#include <hip/hip_runtime.h>

#define B_   8
#define N_   1024
#define F0_  56
#define D_   70
#define DK_  96      // bf16 K-padded row stride (3 x 32)
#define DFC_ 128

typedef __attribute__((ext_vector_type(8))) short bf16x8;
typedef __attribute__((ext_vector_type(4))) float f32x4;
typedef __attribute__((ext_vector_type(16))) float f32x16;
typedef unsigned short ushortT;
typedef _Float16 f16T;

__device__ __forceinline__ short f2bf(float x) {
  unsigned u = __builtin_bit_cast(unsigned, x);
  u += 0x7FFF + ((u >> 16) & 1);
  return (short)(u >> 16);
}
__device__ __forceinline__ float bfdec(unsigned u16bits) {
  unsigned v = u16bits << 16;
  return __builtin_bit_cast(float, v);
}
__device__ __forceinline__ ushortT f2h(float x) {
  f16T h = (f16T)x; return __builtin_bit_cast(ushortT, h);
}
__device__ __forceinline__ float h2f(ushortT u) {
  return (float)__builtin_bit_cast(f16T, u);
}
__device__ __forceinline__ float dot4(float4 a, float4 b) {
  return a.x * b.x + a.y * b.y + a.z * b.z + a.w * b.w;
}

// ---- prep_all: adj tiles (8192 blocks) | weights | hT pad | few | pooled=0
__global__ __launch_bounds__(256) void prep_all(
    const float* __restrict__ A1, const float* __restrict__ A2,
    const float* __restrict__ mup, const float* __restrict__ devp,
    const float* __restrict__ gW, const float* __restrict__ gA,
    const float* __restrict__ few,
    ushortT* __restrict__ adj_t,
    short* __restrict__ Wb16, short* __restrict__ Atb16, short* __restrict__ fewb16,
    short* __restrict__ hT, float* __restrict__ pooled)
{
  const int bid = blockIdx.x;
  const int tid = threadIdx.x;
  if (bid >= 32 * 32 * B_) {
    const int e = bid - 32 * 32 * B_;
    if (e < 8) {
      const int k = e & 3;
      const bool isW = e < 4;
      short* dst = (isW ? Wb16 : Atb16) + (size_t)k * 80 * 96;
      const float* src = (isW ? gW : gA) + (size_t)k * D_ * D_;
      for (int i = tid; i < 80 * 96; i += 256) {
        const int d = i / 96, m = i - (i / 96) * 96;
        float v = 0.f;
        if (d < D_ && m < D_) v = isW ? src[d * D_ + m] : src[m * D_ + d];
        dst[i] = f2bf(v);
      }
    } else if (e < 16) {
      const int b = e - 8;
      uint2* p = (uint2*)(hT + ((size_t)(b * 96 + 80)) * N_);
      for (int i = tid; i < 16 * N_ / 4; i += 256) p[i] = (uint2){0, 0};
    } else {
      for (int i = tid; i < 80 * 64; i += 256) {
        const int d = i >> 6, m = i & 63;
        fewb16[i] = f2bf((d < D_ && m < F0_) ? few[d * F0_ + m] : 0.f);
      }
      for (int i = tid; i < B_ * D_; i += 256) pooled[i] = 0.f;
    }
    return;
  }
  const int it = bid & 31, jt = (bid >> 5) & 31, b = bid >> 10;
  const int i0 = it * 32, j0 = jt * 32;
  const int jrel = tid >> 3, iq = tid & 7;
  const float mu = mup[0], idev = 1.0f / devp[0];
  const size_t base = ((size_t)b * N_ + j0 + jrel) * N_ + i0 + iq * 4;
  const float4 a1 = *(const float4*)(A1 + base);
  const float4 a2 = *(const float4*)(A2 + base);
  const float a1v[4] = {a1.x, a1.y, a1.z, a1.w};
  const float a2v[4] = {a2.x, a2.y, a2.z, a2.w};
  ushortT o[4];
#pragma unroll
  for (int k = 0; k < 4; k++) {
    const float rbf = (a2v[k] <= 10.f) ? __expf(-(a2v[k] - mu) * (a2v[k] - mu) * idev) : 0.f;
    const float adj1 = rbf + a1v[k];
    ushortT u = ((ushortT)f2bf(adj1)) & 0xFFFE;
    if (a1v[k] > 0.f) u |= 1;
    o[k] = u;
  }
  *(uint2*)(adj_t + ((size_t)(b * 32 + jt) * 32 + it) * 1024 + jrel * 32 + iq * 4) =
      *(uint2*)o;
}

// -- fused [featem|combine] + h + hA + hT via MFMA (16 rows, 2 waves, nt-split)
#define GR 16
template<int MODE>
__global__ __launch_bounds__(128) void gatmm_mfma(
    float* __restrict__ x, const float* __restrict__ H, const short* __restrict__ fewb,
    const ushortT* __restrict__ hp1p, const ushortT* __restrict__ hp2p, int JC,
    const float* __restrict__ g1, const float* __restrict__ g2w, const float* __restrict__ g2b,
    const short* __restrict__ Wb, const short* __restrict__ Atb,
    short* __restrict__ hb16, short* __restrict__ hAb16, short* __restrict__ hT)
{
  const int tid = threadIdx.x;
  const int w = tid >> 6, lane = tid & 63;
  const int lr = lane & 15, kg = lane >> 4;
  const int r0 = blockIdx.x * GR;
  const int b = r0 >> 10, n0 = r0 & (N_ - 1);

  __shared__ __align__(16) short sxb[GR][104];
  __shared__ __align__(16) short shl[GR][104];

  for (int i = tid; i < 160; i += 128) {
    const int r = i / 10, c = i - (i / 10) * 10;
    *(uint2*)&sxb[r][64 + c * 4] = (uint2){0, 0};
    *(uint2*)&shl[r][64 + c * 4] = (uint2){0, 0};
  }

  if (MODE == 0) {
    for (int i = tid; i < GR * 64; i += 128) {
      const int r = i >> 6, c = i & 63;
      shl[r][c] = f2bf((c < F0_) ? H[(size_t)(r0 + r) * F0_ + c] : 0.f);
    }
    __syncthreads();
    bf16x8 hf[2];
#pragma unroll
    for (int ks = 0; ks < 2; ks++)
      hf[ks] = *(const bf16x8*)&shl[lr][ks * 32 + kg * 8];
    for (int nt = w; nt < 5; nt += 2) {
      f32x4 accf = (f32x4){0.f, 0.f, 0.f, 0.f};
#pragma unroll
      for (int ks = 0; ks < 2; ks++) {
        bf16x8 bw = *(const bf16x8*)(fewb + (size_t)(nt * 16 + lr) * 64 + ks * 32 + kg * 8);
        accf = __builtin_amdgcn_mfma_f32_16x16x32_bf16(hf[ks], bw, accf, 0, 0, 0);
      }
#pragma unroll
      for (int r = 0; r < 4; r++) {
        const int i = kg * 4 + r, d = nt * 16 + lr;
        if (d < D_) x[(size_t)(r0 + i) * D_ + d] = accf[r];
        sxb[i][d] = f2bf(accf[r]);
      }
    }
  } else {
    const int lt = tid & 15, gg = tid >> 4;
#pragma unroll
    for (int rg = 0; rg < 2; rg++) {
      const int row = gg * 2 + rg;
      const int grow = r0 + row;
      float s1[5], s2[5], xv[5];
#pragma unroll
      for (int q = 0; q < 5; q++) { s1[q] = 0.f; s2[q] = 0.f; xv[q] = 0.f; }
      for (int jc = 0; jc < JC; jc++) {
        const size_t bp = ((size_t)jc * (B_ * N_) + grow) * 80 + lt;
#pragma unroll
        for (int q = 0; q < 5; q++) {
          s1[q] += bfdec(hp1p[bp + 16 * q]);
          s2[q] += bfdec(hp2p[bp + 16 * q]);
        }
      }
      float d1 = 0.f, d2 = 0.f, d3 = 0.f;
#pragma unroll
      for (int q = 0; q < 5; q++) {
        const int d = lt + 16 * q;
        if (d < D_) {
          s1[q] = fmaxf(s1[q], 0.f); s2[q] = fmaxf(s2[q], 0.f);
          xv[q] = x[(size_t)grow * D_ + d];
          d1 += xv[q] * g1[d]; d2 += s1[q] * g2w[d]; d3 += s2[q] * g2w[d];
        }
      }
#pragma unroll
      for (int off = 1; off < 16; off <<= 1) {
        d1 += __shfl_xor(d1, off); d2 += __shfl_xor(d2, off); d3 += __shfl_xor(d3, off);
      }
      const float bb = g2b[0];
      const float c1 = 1.f / (1.f + __expf(-(d1 + d2 + bb)));
      const float c2 = 1.f / (1.f + __expf(-(d1 + d3 + bb)));
#pragma unroll
      for (int q = 0; q < 5; q++) {
        const int d = lt + 16 * q;
        if (d < D_) {
          const float xn = (c1 * xv[q] + (1.f - c1) * s1[q]) - (c2 * xv[q] + (1.f - c2) * s2[q]);
          x[(size_t)grow * D_ + d] = xn;
          sxb[row][d] = f2bf(xn);
        }
      }
    }
  }
  __syncthreads();

  // GEMM1: h = x @ W^T
  bf16x8 af[3];
#pragma unroll
  for (int ks = 0; ks < 3; ks++)
    af[ks] = *(const bf16x8*)&sxb[lr][ks * 32 + kg * 8];
  for (int nt = w; nt < 5; nt += 2) {
    f32x4 acc = (f32x4){0.f, 0.f, 0.f, 0.f};
#pragma unroll
    for (int ks = 0; ks < 3; ks++) {
      bf16x8 bw = *(const bf16x8*)(Wb + (size_t)(nt * 16 + lr) * 96 + ks * 32 + kg * 8);
      acc = __builtin_amdgcn_mfma_f32_16x16x32_bf16(af[ks], bw, acc, 0, 0, 0);
    }
#pragma unroll
    for (int r = 0; r < 4; r++)
      shl[kg * 4 + r][nt * 16 + lr] = f2bf(acc[r]);
  }
  __syncthreads();

  for (int i = tid; i < GR * 12; i += 128) {
    const int r = i / 12, seg = i - (i / 12) * 12;
    *(bf16x8*)(hb16 + (size_t)(r0 + r) * DK_ + seg * 8) = *(const bf16x8*)&shl[r][seg * 8];
  }
  for (int i = tid; i < 160; i += 128) {
    const int d = i >> 1, ng = i & 1;
    short tmp[8];
#pragma unroll
    for (int k = 0; k < 8; k++) tmp[k] = shl[ng * 8 + k][d];
    *(bf16x8*)(hT + ((size_t)(b * 96 + d)) * N_ + n0 + ng * 8) = *(bf16x8*)tmp;
  }

  // GEMM2: hA = h @ A
  bf16x8 ah[3];
#pragma unroll
  for (int ks = 0; ks < 3; ks++)
    ah[ks] = *(const bf16x8*)&shl[lr][ks * 32 + kg * 8];
  for (int nt = w; nt < 5; nt += 2) {
    f32x4 acc2 = (f32x4){0.f, 0.f, 0.f, 0.f};
#pragma unroll
    for (int ks = 0; ks < 3; ks++) {
      bf16x8 bw = *(const bf16x8*)(Atb + (size_t)(nt * 16 + lr) * 96 + ks * 32 + kg * 8);
      acc2 = __builtin_amdgcn_mfma_f32_16x16x32_bf16(ah[ks], bw, acc2, 0, 0, 0);
    }
#pragma unroll
    for (int r = 0; r < 4; r++)
      sxb[kg * 4 + r][nt * 16 + lr] = f2bf(acc2[r]);
  }
  __syncthreads();
  for (int i = tid; i < GR * 12; i += 128) {
    const int r = i / 12, seg = i - (i / 12) * 12;
    *(bf16x8*)(hAb16 + (size_t)(r0 + r) * DK_ + seg * 8) = *(const bf16x8*)&sxb[r][seg * 8];
  }
}

// ---------------- passE: 32x32 MFMA per wave; E tiles fp16 + masked softmax stats
// D layout: col = lane&31 (=j), row i = (reg&3) + 8*(reg>>2) + 4*(lane>>5)
__global__ __launch_bounds__(256) void passE_mfma(
    const ushortT* __restrict__ adj_t,
    const short* __restrict__ hb16, const short* __restrict__ hAb16,
    ushortT* __restrict__ Et,
    float* __restrict__ M1p, float* __restrict__ S1p,
    float* __restrict__ M2p, float* __restrict__ S2p)
{
  const int jt = blockIdx.x, ic = blockIdx.y, b = blockIdx.z;
  const int tid = threadIdx.x, w = tid >> 6, lane = tid & 63;
  const int jr = lane & 31, kh = lane >> 5;
  const int j0 = jt * 32;
  const short* hb  = hb16  + (size_t)b * N_ * DK_;
  const short* hAb = hAb16 + (size_t)b * N_ * DK_;

  // B-frags: j rows (k = ks*16 + kh*8 + e)
  bf16x8 b_h[6], b_hA[6];
  {
    const short* p = hb  + (size_t)(j0 + jr) * DK_ + kh * 8;
    const short* q = hAb + (size_t)(j0 + jr) * DK_ + kh * 8;
#pragma unroll
    for (int ks = 0; ks < 6; ks++) {
      b_h[ks]  = *(const bf16x8*)(p + ks * 16);
      b_hA[ks] = *(const bf16x8*)(q + ks * 16);
    }
  }
  const int itg = ic * 4 + w;
  const int i0 = itg * 32;
  const short* pa = hAb + (size_t)(i0 + jr) * DK_ + kh * 8;
  const short* ph = hb  + (size_t)(i0 + jr) * DK_ + kh * 8;
  const size_t tbase = ((size_t)(b * 32 + jt) * 32 + itg) * 1024 + jr * 32 + kh * 4;
  uint2 aq[4];
#pragma unroll
  for (int q = 0; q < 4; q++) aq[q] = *(const uint2*)(adj_t + tbase + q * 8);

  f32x16 acc;
#pragma unroll
  for (int r = 0; r < 16; r++) acc[r] = 0.f;
#pragma unroll
  for (int ks = 0; ks < 6; ks++) {
    bf16x8 a = *(const bf16x8*)(pa + ks * 16);
    acc = __builtin_amdgcn_mfma_f32_32x32x16_bf16(a, b_h[ks], acc, 0, 0, 0);
  }
#pragma unroll
  for (int ks = 0; ks < 6; ks++) {
    bf16x8 a = *(const bf16x8*)(ph + ks * 16);
    acc = __builtin_amdgcn_mfma_f32_32x32x16_bf16(a, b_hA[ks], acc, 0, 0, 0);
  }

  // round -> fp16 store; gates from adj (irel = q*8 + kh*4 + e  == acc reg map)
  float Ev[16]; bool g1[16], g2[16];
#pragma unroll
  for (int q = 0; q < 4; q++) {
    ushortT ev16[4];
    const ushortT uu[4] = {(ushortT)(aq[q].x & 0xFFFF), (ushortT)(aq[q].x >> 16),
                           (ushortT)(aq[q].y & 0xFFFF), (ushortT)(aq[q].y >> 16)};
#pragma unroll
    for (int e = 0; e < 4; e++) {
      const int r = q * 4 + e;
      ev16[e] = f2h(acc[r]);
      Ev[r] = h2f(ev16[e]);
      g1[r] = (uu[e] & 0xFFFEu) != 0;
      g2[r] = (uu[e] & 1u) != 0;
    }
    const unsigned lo = (unsigned)ev16[0] | ((unsigned)ev16[1] << 16);
    const unsigned hi = (unsigned)ev16[2] | ((unsigned)ev16[3] << 16);
    *(uint2*)(Et + tbase + q * 8) = (uint2){lo, hi};
  }

  // masked stats over i (16 in-lane + lane^32), per column j
  float M1r = -3.0e38f, M2r = -3.0e38f;
#pragma unroll
  for (int r = 0; r < 16; r++) {
    M1r = g1[r] ? fmaxf(M1r, Ev[r]) : M1r;
    M2r = g2[r] ? fmaxf(M2r, Ev[r]) : M2r;
  }
  float S1r = 0.f, S2r = 0.f;
#pragma unroll
  for (int r = 0; r < 16; r++) {
    S1r += g1[r] ? __expf(Ev[r] - M1r) : 0.f;
    S2r += g2[r] ? __expf(Ev[r] - M2r) : 0.f;
  }
  {
    float Mo = __shfl_xor(M1r, 32), So = __shfl_xor(S1r, 32);
    float nM = fmaxf(M1r, Mo);
    S1r = S1r * __expf(M1r - nM) + So * __expf(Mo - nM); M1r = nM;
    Mo = __shfl_xor(M2r, 32); So = __shfl_xor(S2r, 32);
    nM = fmaxf(M2r, Mo);
    S2r = S2r * __expf(M2r - nM) + So * __expf(Mo - nM); M2r = nM;
  }
  __shared__ float sM[2][4][32], sS[2][4][32];
  if (lane < 32) {
    sM[0][w][jr] = M1r; sS[0][w][jr] = S1r;
    sM[1][w][jr] = M2r; sS[1][w][jr] = S2r;
  }
  __syncthreads();
  if (tid < 64) {
    const int msk = tid >> 5, c = tid & 31;
    float M = sM[msk][0][c], S = sS[msk][0][c];
#pragma unroll
    for (int wv = 1; wv < 4; wv++) {
      const float m = sM[msk][wv][c], s = sS[msk][wv][c];
      const float nM = fmaxf(M, m);
      S = S * __expf(M - nM) + s * __expf(m - nM); M = nM;
    }
    const size_t o = ((size_t)b * 8 + ic) * N_ + j0 + c;
    if (msk == 0) { M1p[o] = M; S1p[o] = S; }
    else          { M2p[o] = M; S2p[o] = S; }
  }
}

// --------------------- passPV: prefetched E/adj tiles, weights, PV MFMA
#define NJT 4
__global__ __launch_bounds__(256) void passPV_mfma(
    const ushortT* __restrict__ adj_t, const ushortT* __restrict__ Et,
    const short* __restrict__ hT16,
    const float* __restrict__ M1p, const float* __restrict__ S1p,
    const float* __restrict__ M2p, const float* __restrict__ S2p,
    ushortT* __restrict__ hp1p, ushortT* __restrict__ hp2p)
{
  const int it = blockIdx.x, jc = blockIdx.y, b = blockIdx.z;
  const int tid = threadIdx.x, w = tid >> 6, lane = tid & 63;
  const int lr = lane & 15, kg = lane >> 4;
  const int ih = w >> 1, jh = w & 1;
  const int dbase = (w & 1) * 3;
  const int jbase = jc * NJT * 32;
  const int lofs = (jh * 16 + lr) * 32 + (ih * 16 + kg * 4);

  __shared__ float sMS[4][NJT * 32];
  for (int idx = tid; idx < NJT * 32; idx += 256) {
    const int col = jbase + idx;
    float M = -3.0e38f, S = 0.f;
#pragma unroll
    for (int q = 0; q < 8; q++) {
      const float m = M1p[((size_t)b * 8 + q) * N_ + col];
      const float s = S1p[((size_t)b * 8 + q) * N_ + col];
      const float nM = fmaxf(M, m);
      S = S * __expf(M - nM) + s * __expf(m - nM); M = nM;
    }
    sMS[0][idx] = M; sMS[1][idx] = 1.0f / S;
    M = -3.0e38f; S = 0.f;
#pragma unroll
    for (int q = 0; q < 8; q++) {
      const float m = M2p[((size_t)b * 8 + q) * N_ + col];
      const float s = S2p[((size_t)b * 8 + q) * N_ + col];
      const float nM = fmaxf(M, m);
      S = S * __expf(M - nM) + s * __expf(m - nM); M = nM;
    }
    sMS[2][idx] = M; sMS[3][idx] = 1.0f / S;
  }

  const short* hTb = hT16 + (size_t)b * DK_ * N_;
  f32x4 acc[2][3];
#pragma unroll
  for (int m = 0; m < 2; m++)
#pragma unroll
    for (int q = 0; q < 3; q++) acc[m][q] = (f32x4){0.f, 0.f, 0.f, 0.f};

  __shared__ short wlds[2][2][32][40];
  __syncthreads();

  size_t tb = ((size_t)(b * 32 + jc * NJT) * 32 + it) * 1024 + lofs;
  uint2 eraw = *(const uint2*)(Et + tb);
  uint2 araw = *(const uint2*)(adj_t + tb);

#pragma unroll
  for (int t = 0; t < NJT; ++t) {
    const int j0 = jbase + t * 32;
    const int par = t & 1;
    bf16x8 bt[3];
#pragma unroll
    for (int q = 0; q < 3; q++)
      bt[q] = *(const bf16x8*)(hTb + (size_t)((dbase + q) * 16 + lr) * N_ + j0 + kg * 8);
    uint2 eN, aN;
    if (t + 1 < NJT) {
      const size_t tbn = ((size_t)(b * 32 + jc * NJT + t + 1) * 32 + it) * 1024 + lofs;
      eN = *(const uint2*)(Et + tbn);
      aN = *(const uint2*)(adj_t + tbn);
    }

    const ushortT ev[4] = {(ushortT)(eraw.x & 0xFFFF), (ushortT)(eraw.x >> 16),
                           (ushortT)(eraw.y & 0xFFFF), (ushortT)(eraw.y >> 16)};
    const ushortT uu[4] = {(ushortT)(araw.x & 0xFFFF), (ushortT)(araw.x >> 16),
                           (ushortT)(araw.y & 0xFFFF), (ushortT)(araw.y >> 16)};
    const int jrel = t * 32 + jh * 16 + lr;
    const float M1j = sMS[0][jrel], is1 = sMS[1][jrel];
    const float M2j = sMS[2][jrel], is2 = sMS[3][jrel];

    short w1v[4], w2v[4];
#pragma unroll
    for (int r = 0; r < 4; r++) {
      const float e = h2f(ev[r]);
      const float adj1v = bfdec(uu[r] & 0xFFFEu);
      const bool gon1 = (uu[r] & 0xFFFEu) != 0, gon2 = (uu[r] & 1u) != 0;
      w1v[r] = f2bf(gon1 ? __expf(e - M1j) * adj1v * is1 : 0.f);
      w2v[r] = f2bf(gon2 ? __expf(e - M2j) * is2 : 0.f);
    }
#pragma unroll
    for (int r = 0; r < 4; r++) {
      wlds[par][0][ih * 16 + kg * 4 + r][jh * 16 + lr] = w1v[r];
      wlds[par][1][ih * 16 + kg * 4 + r][jh * 16 + lr] = w2v[r];
    }
    __syncthreads();
#pragma unroll
    for (int m = 0; m < 2; m++) {
      bf16x8 af = *(const bf16x8*)&wlds[par][m][ih * 16 + lr][kg * 8];
#pragma unroll
      for (int q = 0; q < 3; q++)
        acc[m][q] = __builtin_amdgcn_mfma_f32_16x16x32_bf16(af, bt[q], acc[m][q], 0, 0, 0);
    }
    eraw = eN; araw = aN;
  }
  const int i0 = it * 32;
#pragma unroll
  for (int m = 0; m < 2; m++) {
#pragma unroll
    for (int q = 0; q < 3; q++) {
      const int dt = dbase + q;
      if (dt < 5) {
        ushortT* dst = (m ? hp2p : hp1p) +
            (((size_t)jc * B_ + b) * N_ + i0 + ih * 16 + kg * 4) * 80 + dt * 16 + lr;
#pragma unroll
        for (int r = 0; r < 4; r++) dst[(size_t)r * 80] = (ushortT)f2bf(acc[m][q][r]);
      }
    }
  }
}

// ------------- final-layer combine fused with masked pool (atomic into pooled)
__global__ __launch_bounds__(256) void combine_pool(
    const float* __restrict__ x,
    const ushortT* __restrict__ hp1p, const ushortT* __restrict__ hp2p, int JC,
    const float* __restrict__ g1, const float* __restrict__ g2w,
    const float* __restrict__ g2b,
    const float* __restrict__ V, float* __restrict__ pooled)
{
  const int r = blockIdx.x * 4 + (threadIdx.x >> 6);
  const int t = threadIdx.x & 63;
  __shared__ float sAcc[D_];
  if (threadIdx.x < D_) sAcc[threadIdx.x] = 0.f;
  __syncthreads();
  float s1a = 0.f, s2a = 0.f, s1b = 0.f, s2b = 0.f;
  for (int q = 0; q < JC; q++) {
    const size_t base = ((size_t)q * (B_ * N_) + r) * 80;
    s1a += bfdec(hp1p[base + t]);
    s2a += bfdec(hp2p[base + t]);
    if (t < D_ - 64) {
      s1b += bfdec(hp1p[base + 64 + t]);
      s2b += bfdec(hp2p[base + 64 + t]);
    }
  }
  const float a0 = fmaxf(s1a, 0.f), b0 = fmaxf(s2a, 0.f);
  const float a1v = fmaxf(s1b, 0.f), b1v = fmaxf(s2b, 0.f);
  const float* xr = x + (size_t)r * D_;
  const float x0 = xr[t];
  float d1 = x0 * g1[t], d2 = a0 * g2w[t], d3 = b0 * g2w[t];
  float x1 = 0.f;
  if (t < D_ - 64) {
    x1 = xr[64 + t];
    d1 += x1 * g1[64 + t]; d2 += a1v * g2w[64 + t]; d3 += b1v * g2w[64 + t];
  }
#pragma unroll
  for (int off = 1; off < 64; off <<= 1) {
    d1 += __shfl_xor(d1, off);
    d2 += __shfl_xor(d2, off);
    d3 += __shfl_xor(d3, off);
  }
  const float bb = g2b[0];
  const float c1 = 1.f / (1.f + __expf(-(d1 + d2 + bb)));
  const float c2 = 1.f / (1.f + __expf(-(d1 + d3 + bb)));
  const float Vr = V[r];
  const float o0 = (c1 * x0 + (1.f - c1) * a0) - (c2 * x0 + (1.f - c2) * b0);
  atomicAdd(&sAcc[t], o0 * Vr);
  if (t < D_ - 64) {
    const float o1 = (c1 * x1 + (1.f - c1) * a1v) - (c2 * x1 + (1.f - c2) * b1v);
    atomicAdd(&sAcc[64 + t], o1 * Vr);
  }
  __syncthreads();
  if (threadIdx.x < D_) {
    const int b = blockIdx.x >> 8;
    atomicAdd(&pooled[b * D_ + threadIdx.x], sAcc[threadIdx.x]);
  }
}

// ------------- MLP head: 8 blocks (one per batch row) x 1024 thr, 8-way sliced
__global__ __launch_bounds__(1024) void fc_kernel(
    const float* __restrict__ pooled,
    const float* __restrict__ w0, const float* __restrict__ b0,
    const float* __restrict__ w1, const float* __restrict__ b1,
    const float* __restrict__ w2, const float* __restrict__ b2,
    const float* __restrict__ w3, const float* __restrict__ b3,
    float* __restrict__ out)
{
  const int b = blockIdx.x;
  const int t = threadIdx.x;
  const int o = t >> 3, s = t & 7;
  __shared__ float pin[D_];
  __shared__ float part[DFC_][9];
  __shared__ float bufA[DFC_], bufB[DFC_];
  if (t < D_) pin[t] = pooled[b * D_ + t];
  __syncthreads();
  {
    float a = 0.f;
    const int m0 = s * 9, m1 = (m0 + 9 < D_) ? m0 + 9 : D_;
    for (int m = m0; m < m1; m++) a += pin[m] * w0[o * D_ + m];
    part[o][s] = a;
  }
  __syncthreads();
  if (t < DFC_) {
    float a = b0[t];
#pragma unroll
    for (int q = 0; q < 8; q++) a += part[t][q];
    bufA[t] = fmaxf(a, 0.f);
  }
  __syncthreads();
  {
    float a = 0.f;
    const float4* wr = (const float4*)(w1 + o * DFC_ + s * 16);
    const float4* br = (const float4*)&bufA[s * 16];
#pragma unroll
    for (int m4 = 0; m4 < 4; m4++) a += dot4(br[m4], wr[m4]);
    part[o][s] = a;
  }
  __syncthreads();
  if (t < DFC_) {
    float a = b1[t];
#pragma unroll
    for (int q = 0; q < 8; q++) a += part[t][q];
    bufB[t] = fmaxf(a, 0.f);
  }
  __syncthreads();
  {
    float a = 0.f;
    const float4* wr = (const float4*)(w2 + o * DFC_ + s * 16);
    const float4* br = (const float4*)&bufB[s * 16];
#pragma unroll
    for (int m4 = 0; m4 < 4; m4++) a += dot4(br[m4], wr[m4]);
    part[o][s] = a;
  }
  __syncthreads();
  if (t < DFC_) {
    float a = b2[t];
#pragma unroll
    for (int q = 0; q < 8; q++) a += part[t][q];
    bufA[t] = fmaxf(a, 0.f);
  }
  __syncthreads();
  if (t < 32) {
    const float4 wv = *(const float4*)(w3 + t * 4);
    const float4 bv = *(const float4*)&bufA[t * 4];
    float a = dot4(bv, wv);
    a += __shfl_xor(a, 1); a += __shfl_xor(a, 2); a += __shfl_xor(a, 4);
    a += __shfl_xor(a, 8); a += __shfl_xor(a, 16);
    if (t == 0) out[b] = 1.f / (1.f + __expf(-(a + b3[0])));
  }
}

// ----------------------------------------------------------------------
extern "C" void kernel_launch(void* const* d_in, const int* in_sizes, int n_in,
                              void* d_out, int out_size, void* d_ws, size_t ws_size,
                              hipStream_t stream)
{
  const float* H     = (const float*)d_in[0];
  const float* A1    = (const float*)d_in[1];
  const float* A2    = (const float*)d_in[2];
  const float* V     = (const float*)d_in[3];
  const float* few   = (const float*)d_in[4];
  const float* mup   = (const float*)d_in[5];
  const float* devp  = (const float*)d_in[6];
  const float* gW    = (const float*)d_in[7];
  const float* gA    = (const float*)d_in[8];
  const float* g1    = (const float*)d_in[9];
  const float* g2w   = (const float*)d_in[10];
  const float* g2b   = (const float*)d_in[11];
  const float* w0 = (const float*)d_in[12]; const float* b0 = (const float*)d_in[13];
  const float* w1 = (const float*)d_in[14]; const float* b1 = (const float*)d_in[15];
  const float* w2 = (const float*)d_in[16]; const float* b2 = (const float*)d_in[17];
  const float* w3 = (const float*)d_in[18]; const float* b3 = (const float*)d_in[19];
  float* outp = (float*)d_out;

  float* ws = (float*)d_ws;
  // fixed layout (float offsets)
  float*   x      = ws;                         // 573440
  short*   hb16   = (short*)(ws + 573440);
  short*   hAb16  = (short*)(ws + 966656);
  short*   hT16   = (short*)(ws + 1359872);
  short*   Wb16   = (short*)(ws + 1753088);
  short*   Atb16  = (short*)(ws + 1768448);
  short*   fewb16 = (short*)(ws + 1783808);     // 80*64 bf16 -> 1786368
  float*   M1p    = ws + 1786368;               // 8*B*N each
  float*   S1p    = ws + 1851904;
  float*   M2p    = ws + 1917440;
  float*   S2p    = ws + 1982976;
  float*   pooled = ws + 2048512;               // -> 2049088
  ushortT* adj_t  = (ushortT*)(ws + 2049088);   // 8M u16 -> 6243392
  ushortT* Et     = (ushortT*)(ws + 6243392);   // 8M u16 -> 10437696
  const int JC = 8;                              // = 32 / NJT
  ushortT* hp1p   = (ushortT*)(ws + 10437696);
  ushortT* hp2p   = hp1p + (size_t)JC * 655360u;
  const size_t need = (size_t)10437696u * 4u + (size_t)JC * 655360u * 4u;
  if (ws_size < need) return;
  const int ROWS = B_ * N_;

  prep_all<<<32 * 32 * B_ + 17, 256, 0, stream>>>(A1, A2, mup, devp, gW, gA, few,
      adj_t, Wb16, Atb16, fewb16, hT16, pooled);

  for (int k = 0; k < 4; k++) {
    const short* Wk  = Wb16  + (size_t)k * 80 * 96;
    const short* Atk = Atb16 + (size_t)k * 80 * 96;
    if (k == 0)
      gatmm_mfma<0><<<ROWS / GR, 128, 0, stream>>>(
          x, H, fewb16, nullptr, nullptr, 0, nullptr, nullptr, nullptr,
          Wk, Atk, hb16, hAb16, hT16);
    else
      gatmm_mfma<1><<<ROWS / GR, 128, 0, stream>>>(
          x, nullptr, nullptr, hp1p, hp2p, JC,
          g1 + (size_t)(k - 1) * D_, g2w + (size_t)(k - 1) * D_, g2b + (k - 1),
          Wk, Atk, hb16, hAb16, hT16);
    passE_mfma<<<dim3(32, 8, B_), 256, 0, stream>>>(adj_t, hb16, hAb16, Et,
                                                    M1p, S1p, M2p, S2p);
    passPV_mfma<<<dim3(32, JC, B_), 256, 0, stream>>>(adj_t, Et, hT16,
        M1p, S1p, M2p, S2p, hp1p, hp2p);
  }
  combine_pool<<<ROWS / 4, 256, 0, stream>>>(x, hp1p, hp2p, JC,
      g1 + 3 * D_, g2w + 3 * D_, g2b + 3, V, pooled);
  fc_kernel<<<B_, 1024, 0, stream>>>(pooled, w0, b0, w1, b1, w2, b2, w3, b3, outp);
}

// Round 15
// 253.936 us; speedup vs baseline: 1.0890x; 1.0890x over previous
//
#include <hip/hip_runtime.h>

#define B_   8
#define N_   1024
#define F0_  56
#define D_   70
#define DK_  96      // bf16 K-padded row stride (3 x 32)
#define DFC_ 128

typedef __attribute__((ext_vector_type(8))) short bf16x8;
typedef __attribute__((ext_vector_type(4))) float f32x4;
typedef unsigned short ushortT;
typedef _Float16 f16T;

__device__ __forceinline__ short f2bf(float x) {
  unsigned u = __builtin_bit_cast(unsigned, x);
  u += 0x7FFF + ((u >> 16) & 1);
  return (short)(u >> 16);
}
__device__ __forceinline__ float bfdec(unsigned u16bits) {
  unsigned v = u16bits << 16;
  return __builtin_bit_cast(float, v);
}
__device__ __forceinline__ ushortT f2h(float x) {
  f16T h = (f16T)x; return __builtin_bit_cast(ushortT, h);
}
__device__ __forceinline__ float h2f(ushortT u) {
  return (float)__builtin_bit_cast(f16T, u);
}
__device__ __forceinline__ float dot4(float4 a, float4 b) {
  return a.x * b.x + a.y * b.y + a.z * b.z + a.w * b.w;
}

// ---- prep_all: adj tiles (8192 blocks) | weights | hT pad | few | pooled=0
__global__ __launch_bounds__(256) void prep_all(
    const float* __restrict__ A1, const float* __restrict__ A2,
    const float* __restrict__ mup, const float* __restrict__ devp,
    const float* __restrict__ gW, const float* __restrict__ gA,
    const float* __restrict__ few,
    ushortT* __restrict__ adj_t,
    short* __restrict__ Wb16, short* __restrict__ Atb16, short* __restrict__ fewb16,
    short* __restrict__ hT, float* __restrict__ pooled)
{
  const int bid = blockIdx.x;
  const int tid = threadIdx.x;
  if (bid >= 32 * 32 * B_) {
    const int e = bid - 32 * 32 * B_;
    if (e < 8) {
      const int k = e & 3;
      const bool isW = e < 4;
      short* dst = (isW ? Wb16 : Atb16) + (size_t)k * 80 * 96;
      const float* src = (isW ? gW : gA) + (size_t)k * D_ * D_;
      for (int i = tid; i < 80 * 96; i += 256) {
        const int d = i / 96, m = i - (i / 96) * 96;
        float v = 0.f;
        if (d < D_ && m < D_) v = isW ? src[d * D_ + m] : src[m * D_ + d];
        dst[i] = f2bf(v);
      }
    } else if (e < 16) {
      const int b = e - 8;
      uint2* p = (uint2*)(hT + ((size_t)(b * 96 + 80)) * N_);
      for (int i = tid; i < 16 * N_ / 4; i += 256) p[i] = (uint2){0, 0};
    } else {
      for (int i = tid; i < 80 * 64; i += 256) {
        const int d = i >> 6, m = i & 63;
        fewb16[i] = f2bf((d < D_ && m < F0_) ? few[d * F0_ + m] : 0.f);
      }
      for (int i = tid; i < B_ * D_; i += 256) pooled[i] = 0.f;
    }
    return;
  }
  const int it = bid & 31, jt = (bid >> 5) & 31, b = bid >> 10;
  const int i0 = it * 32, j0 = jt * 32;
  const int jrel = tid >> 3, iq = tid & 7;
  const float mu = mup[0], idev = 1.0f / devp[0];
  const size_t base = ((size_t)b * N_ + j0 + jrel) * N_ + i0 + iq * 4;
  const float4 a1 = *(const float4*)(A1 + base);
  const float4 a2 = *(const float4*)(A2 + base);
  const float a1v[4] = {a1.x, a1.y, a1.z, a1.w};
  const float a2v[4] = {a2.x, a2.y, a2.z, a2.w};
  ushortT o[4];
#pragma unroll
  for (int k = 0; k < 4; k++) {
    const float rbf = (a2v[k] <= 10.f) ? __expf(-(a2v[k] - mu) * (a2v[k] - mu) * idev) : 0.f;
    const float adj1 = rbf + a1v[k];
    ushortT u = ((ushortT)f2bf(adj1)) & 0xFFFE;
    if (a1v[k] > 0.f) u |= 1;
    o[k] = u;
  }
  *(uint2*)(adj_t + ((size_t)(b * 32 + jt) * 32 + it) * 1024 + jrel * 32 + iq * 4) =
      *(uint2*)o;
}

// -- fused [featem|combine] + h + hA + hT via MFMA (16 rows, 2 waves, nt-split)
#define GR 16
template<int MODE>
__global__ __launch_bounds__(128) void gatmm_mfma(
    float* __restrict__ x, const float* __restrict__ H, const short* __restrict__ fewb,
    const ushortT* __restrict__ hp1p, const ushortT* __restrict__ hp2p, int JC,
    const float* __restrict__ g1, const float* __restrict__ g2w, const float* __restrict__ g2b,
    const short* __restrict__ Wb, const short* __restrict__ Atb,
    short* __restrict__ hb16, short* __restrict__ hAb16, short* __restrict__ hT)
{
  const int tid = threadIdx.x;
  const int w = tid >> 6, lane = tid & 63;
  const int lr = lane & 15, kg = lane >> 4;
  const int r0 = blockIdx.x * GR;
  const int b = r0 >> 10, n0 = r0 & (N_ - 1);

  __shared__ __align__(16) short sxb[GR][104];
  __shared__ __align__(16) short shl[GR][104];

  for (int i = tid; i < 160; i += 128) {
    const int r = i / 10, c = i - (i / 10) * 10;
    *(uint2*)&sxb[r][64 + c * 4] = (uint2){0, 0};
    *(uint2*)&shl[r][64 + c * 4] = (uint2){0, 0};
  }

  if (MODE == 0) {
    for (int i = tid; i < GR * 64; i += 128) {
      const int r = i >> 6, c = i & 63;
      shl[r][c] = f2bf((c < F0_) ? H[(size_t)(r0 + r) * F0_ + c] : 0.f);
    }
    __syncthreads();
    bf16x8 hf[2];
#pragma unroll
    for (int ks = 0; ks < 2; ks++)
      hf[ks] = *(const bf16x8*)&shl[lr][ks * 32 + kg * 8];
    for (int nt = w; nt < 5; nt += 2) {
      f32x4 accf = (f32x4){0.f, 0.f, 0.f, 0.f};
#pragma unroll
      for (int ks = 0; ks < 2; ks++) {
        bf16x8 bw = *(const bf16x8*)(fewb + (size_t)(nt * 16 + lr) * 64 + ks * 32 + kg * 8);
        accf = __builtin_amdgcn_mfma_f32_16x16x32_bf16(hf[ks], bw, accf, 0, 0, 0);
      }
#pragma unroll
      for (int r = 0; r < 4; r++) {
        const int i = kg * 4 + r, d = nt * 16 + lr;
        if (d < D_) x[(size_t)(r0 + i) * D_ + d] = accf[r];
        sxb[i][d] = f2bf(accf[r]);
      }
    }
  } else {
    const int lt = tid & 15, gg = tid >> 4;
#pragma unroll
    for (int rg = 0; rg < 2; rg++) {
      const int row = gg * 2 + rg;
      const int grow = r0 + row;
      float s1[5], s2[5], xv[5];
#pragma unroll
      for (int q = 0; q < 5; q++) { s1[q] = 0.f; s2[q] = 0.f; xv[q] = 0.f; }
      for (int jc = 0; jc < JC; jc++) {
        const size_t bp = ((size_t)jc * (B_ * N_) + grow) * 80 + lt;
#pragma unroll
        for (int q = 0; q < 5; q++) {
          s1[q] += bfdec(hp1p[bp + 16 * q]);
          s2[q] += bfdec(hp2p[bp + 16 * q]);
        }
      }
      float d1 = 0.f, d2 = 0.f, d3 = 0.f;
#pragma unroll
      for (int q = 0; q < 5; q++) {
        const int d = lt + 16 * q;
        if (d < D_) {
          s1[q] = fmaxf(s1[q], 0.f); s2[q] = fmaxf(s2[q], 0.f);
          xv[q] = x[(size_t)grow * D_ + d];
          d1 += xv[q] * g1[d]; d2 += s1[q] * g2w[d]; d3 += s2[q] * g2w[d];
        }
      }
#pragma unroll
      for (int off = 1; off < 16; off <<= 1) {
        d1 += __shfl_xor(d1, off); d2 += __shfl_xor(d2, off); d3 += __shfl_xor(d3, off);
      }
      const float bb = g2b[0];
      const float c1 = 1.f / (1.f + __expf(-(d1 + d2 + bb)));
      const float c2 = 1.f / (1.f + __expf(-(d1 + d3 + bb)));
#pragma unroll
      for (int q = 0; q < 5; q++) {
        const int d = lt + 16 * q;
        if (d < D_) {
          const float xn = (c1 * xv[q] + (1.f - c1) * s1[q]) - (c2 * xv[q] + (1.f - c2) * s2[q]);
          x[(size_t)grow * D_ + d] = xn;
          sxb[row][d] = f2bf(xn);
        }
      }
    }
  }
  __syncthreads();

  // GEMM1: h = x @ W^T
  bf16x8 af[3];
#pragma unroll
  for (int ks = 0; ks < 3; ks++)
    af[ks] = *(const bf16x8*)&sxb[lr][ks * 32 + kg * 8];
  for (int nt = w; nt < 5; nt += 2) {
    f32x4 acc = (f32x4){0.f, 0.f, 0.f, 0.f};
#pragma unroll
    for (int ks = 0; ks < 3; ks++) {
      bf16x8 bw = *(const bf16x8*)(Wb + (size_t)(nt * 16 + lr) * 96 + ks * 32 + kg * 8);
      acc = __builtin_amdgcn_mfma_f32_16x16x32_bf16(af[ks], bw, acc, 0, 0, 0);
    }
#pragma unroll
    for (int r = 0; r < 4; r++)
      shl[kg * 4 + r][nt * 16 + lr] = f2bf(acc[r]);
  }
  __syncthreads();

  for (int i = tid; i < GR * 12; i += 128) {
    const int r = i / 12, seg = i - (i / 12) * 12;
    *(bf16x8*)(hb16 + (size_t)(r0 + r) * DK_ + seg * 8) = *(const bf16x8*)&shl[r][seg * 8];
  }
  for (int i = tid; i < 160; i += 128) {
    const int d = i >> 1, ng = i & 1;
    short tmp[8];
#pragma unroll
    for (int k = 0; k < 8; k++) tmp[k] = shl[ng * 8 + k][d];
    *(bf16x8*)(hT + ((size_t)(b * 96 + d)) * N_ + n0 + ng * 8) = *(bf16x8*)tmp;
  }

  // GEMM2: hA = h @ A
  bf16x8 ah[3];
#pragma unroll
  for (int ks = 0; ks < 3; ks++)
    ah[ks] = *(const bf16x8*)&shl[lr][ks * 32 + kg * 8];
  for (int nt = w; nt < 5; nt += 2) {
    f32x4 acc2 = (f32x4){0.f, 0.f, 0.f, 0.f};
#pragma unroll
    for (int ks = 0; ks < 3; ks++) {
      bf16x8 bw = *(const bf16x8*)(Atb + (size_t)(nt * 16 + lr) * 96 + ks * 32 + kg * 8);
      acc2 = __builtin_amdgcn_mfma_f32_16x16x32_bf16(ah[ks], bw, acc2, 0, 0, 0);
    }
#pragma unroll
    for (int r = 0; r < 4; r++)
      sxb[kg * 4 + r][nt * 16 + lr] = f2bf(acc2[r]);
  }
  __syncthreads();
  for (int i = tid; i < GR * 12; i += 128) {
    const int r = i / 12, seg = i - (i / 12) * 12;
    *(bf16x8*)(hAb16 + (size_t)(r0 + r) * DK_ + seg * 8) = *(const bf16x8*)&sxb[r][seg * 8];
  }
}

// ---------------- passE: E tiles (stored fp16, tiled) + masked softmax stats
// (16x16 quadrant version — best measured; gates read from adj_t)
__global__ __launch_bounds__(256) void passE_mfma(
    const ushortT* __restrict__ adj_t,
    const short* __restrict__ hb16, const short* __restrict__ hAb16,
    ushortT* __restrict__ Et,
    float* __restrict__ M1p, float* __restrict__ S1p,
    float* __restrict__ M2p, float* __restrict__ S2p)
{
  const int jt = blockIdx.x, ic = blockIdx.y, b = blockIdx.z;
  const int tid = threadIdx.x, w = tid >> 6, lane = tid & 63;
  const int lr = lane & 15, kg = lane >> 4;
  const int ih = w >> 1, jh = w & 1;
  const int j0 = jt * 32;
  const short* hb  = hb16  + (size_t)b * N_ * DK_;
  const short* hAb = hAb16 + (size_t)b * N_ * DK_;

  bf16x8 b_h[3], b_hA[3];
  {
    const short* p = hb  + (size_t)(j0 + jh * 16 + lr) * DK_ + kg * 8;
    const short* q = hAb + (size_t)(j0 + jh * 16 + lr) * DK_ + kg * 8;
#pragma unroll
    for (int ks = 0; ks < 3; ks++) {
      b_h[ks]  = *(const bf16x8*)(p + ks * 32);
      b_hA[ks] = *(const bf16x8*)(q + ks * 32);
    }
  }
  const int i0base = ic * 128;
  const int lofs = (jh * 16 + lr) * 32 + (ih * 16 + kg * 4);
  float Ev[16];
  unsigned g1m = 0, g2m = 0;

#pragma unroll
  for (int iter = 0; iter < 4; iter++) {
    const int i0 = i0base + iter * 32 + ih * 16;
    const short* pa = hAb + (size_t)(i0 + lr) * DK_ + kg * 8;
    const short* ph = hb  + (size_t)(i0 + lr) * DK_ + kg * 8;
    bf16x8 a_hA[3], a_h[3];
#pragma unroll
    for (int ks = 0; ks < 3; ks++) {
      a_hA[ks] = *(const bf16x8*)(pa + ks * 32);
      a_h[ks]  = *(const bf16x8*)(ph + ks * 32);
    }
    const int itg = ic * 4 + iter;
    const size_t tb = ((size_t)(b * 32 + jt) * 32 + itg) * 1024 + lofs;
    const uint2 araw = *(const uint2*)(adj_t + tb);
    f32x4 E = {0.f, 0.f, 0.f, 0.f};
#pragma unroll
    for (int ks = 0; ks < 3; ks++)
      E = __builtin_amdgcn_mfma_f32_16x16x32_bf16(a_hA[ks], b_h[ks], E, 0, 0, 0);
#pragma unroll
    for (int ks = 0; ks < 3; ks++)
      E = __builtin_amdgcn_mfma_f32_16x16x32_bf16(a_h[ks], b_hA[ks], E, 0, 0, 0);
    ushortT ev16[4];
#pragma unroll
    for (int r = 0; r < 4; r++) ev16[r] = f2h(E[r]);
    {
      const unsigned lo = (unsigned)ev16[0] | ((unsigned)ev16[1] << 16);
      const unsigned hi = (unsigned)ev16[2] | ((unsigned)ev16[3] << 16);
      *(uint2*)(Et + tb) = (uint2){lo, hi};
    }
    const ushortT uu[4] = {(ushortT)(araw.x & 0xFFFF), (ushortT)(araw.x >> 16),
                           (ushortT)(araw.y & 0xFFFF), (ushortT)(araw.y >> 16)};
#pragma unroll
    for (int r = 0; r < 4; r++) {
      Ev[iter * 4 + r] = h2f(ev16[r]);
      g1m |= ((uu[r] & 0xFFFEu) ? 1u : 0u) << (iter * 4 + r);
      g2m |= (unsigned)(uu[r] & 1u) << (iter * 4 + r);
    }
  }
  float M1r = -3.0e38f, M2r = -3.0e38f;
#pragma unroll
  for (int k = 0; k < 16; k++) {
    M1r = ((g1m >> k) & 1u) ? fmaxf(M1r, Ev[k]) : M1r;
    M2r = ((g2m >> k) & 1u) ? fmaxf(M2r, Ev[k]) : M2r;
  }
  float S1r = 0.f, S2r = 0.f;
#pragma unroll
  for (int k = 0; k < 16; k++) {
    S1r += ((g1m >> k) & 1u) ? __expf(Ev[k] - M1r) : 0.f;
    S2r += ((g2m >> k) & 1u) ? __expf(Ev[k] - M2r) : 0.f;
  }
#pragma unroll
  for (int off = 16; off <= 32; off <<= 1) {
    float Mo = __shfl_xor(M1r, off), So = __shfl_xor(S1r, off);
    float nM = fmaxf(M1r, Mo);
    S1r = S1r * __expf(M1r - nM) + So * __expf(Mo - nM); M1r = nM;
    Mo = __shfl_xor(M2r, off); So = __shfl_xor(S2r, off);
    nM = fmaxf(M2r, Mo);
    S2r = S2r * __expf(M2r - nM) + So * __expf(Mo - nM); M2r = nM;
  }
  __shared__ float sM[2][4][16], sS[2][4][16];
  if (lane < 16) {
    sM[0][w][lr] = M1r; sS[0][w][lr] = S1r;
    sM[1][w][lr] = M2r; sS[1][w][lr] = S2r;
  }
  __syncthreads();
  if (tid < 32) {
    const int jhh = tid >> 4, l2 = tid & 15;
    const size_t o = ((size_t)b * 8 + ic) * N_ + j0 + jhh * 16 + l2;
    {
      float Ma = sM[0][jhh][l2], Sa = sS[0][jhh][l2];
      float Mb = sM[0][2 + jhh][l2], Sb = sS[0][2 + jhh][l2];
      float nM = fmaxf(Ma, Mb);
      M1p[o] = nM; S1p[o] = Sa * __expf(Ma - nM) + Sb * __expf(Mb - nM);
    }
    {
      float Ma = sM[1][jhh][l2], Sa = sS[1][jhh][l2];
      float Mb = sM[1][2 + jhh][l2], Sb = sS[1][2 + jhh][l2];
      float nM = fmaxf(Ma, Mb);
      M2p[o] = nM; S2p[o] = Sa * __expf(Ma - nM) + Sb * __expf(Mb - nM);
    }
  }
}

// --------------------- passPV: prefetched E/adj tiles, weights, PV MFMA
#define NJT 8
__global__ __launch_bounds__(256) void passPV_mfma(
    const ushortT* __restrict__ adj_t, const ushortT* __restrict__ Et,
    const short* __restrict__ hT16,
    const float* __restrict__ M1p, const float* __restrict__ S1p,
    const float* __restrict__ M2p, const float* __restrict__ S2p,
    ushortT* __restrict__ hp1p, ushortT* __restrict__ hp2p)
{
  const int it = blockIdx.x, jc = blockIdx.y, b = blockIdx.z;
  const int tid = threadIdx.x, w = tid >> 6, lane = tid & 63;
  const int lr = lane & 15, kg = lane >> 4;
  const int ih = w >> 1, jh = w & 1;
  const int dbase = (w & 1) * 3;
  const int jbase = jc * NJT * 32;
  const int lofs = (jh * 16 + lr) * 32 + (ih * 16 + kg * 4);

  __shared__ float sMS[4][NJT * 32];
  for (int idx = tid; idx < NJT * 32; idx += 256) {
    const int col = jbase + idx;
    float M = -3.0e38f, S = 0.f;
#pragma unroll
    for (int q = 0; q < 8; q++) {
      const float m = M1p[((size_t)b * 8 + q) * N_ + col];
      const float s = S1p[((size_t)b * 8 + q) * N_ + col];
      const float nM = fmaxf(M, m);
      S = S * __expf(M - nM) + s * __expf(m - nM); M = nM;
    }
    sMS[0][idx] = M; sMS[1][idx] = 1.0f / S;
    M = -3.0e38f; S = 0.f;
#pragma unroll
    for (int q = 0; q < 8; q++) {
      const float m = M2p[((size_t)b * 8 + q) * N_ + col];
      const float s = S2p[((size_t)b * 8 + q) * N_ + col];
      const float nM = fmaxf(M, m);
      S = S * __expf(M - nM) + s * __expf(m - nM); M = nM;
    }
    sMS[2][idx] = M; sMS[3][idx] = 1.0f / S;
  }

  const short* hTb = hT16 + (size_t)b * DK_ * N_;
  f32x4 acc[2][3];
#pragma unroll
  for (int m = 0; m < 2; m++)
#pragma unroll
    for (int q = 0; q < 3; q++) acc[m][q] = (f32x4){0.f, 0.f, 0.f, 0.f};

  __shared__ short wlds[2][2][32][40];
  __syncthreads();

  size_t tb = ((size_t)(b * 32 + jc * NJT) * 32 + it) * 1024 + lofs;
  uint2 eraw = *(const uint2*)(Et + tb);
  uint2 araw = *(const uint2*)(adj_t + tb);

#pragma unroll
  for (int t = 0; t < NJT; ++t) {
    const int j0 = jbase + t * 32;
    const int par = t & 1;
    bf16x8 bt[3];
#pragma unroll
    for (int q = 0; q < 3; q++)
      bt[q] = *(const bf16x8*)(hTb + (size_t)((dbase + q) * 16 + lr) * N_ + j0 + kg * 8);
    uint2 eN, aN;
    if (t + 1 < NJT) {
      const size_t tbn = ((size_t)(b * 32 + jc * NJT + t + 1) * 32 + it) * 1024 + lofs;
      eN = *(const uint2*)(Et + tbn);
      aN = *(const uint2*)(adj_t + tbn);
    }

    const ushortT ev[4] = {(ushortT)(eraw.x & 0xFFFF), (ushortT)(eraw.x >> 16),
                           (ushortT)(eraw.y & 0xFFFF), (ushortT)(eraw.y >> 16)};
    const ushortT uu[4] = {(ushortT)(araw.x & 0xFFFF), (ushortT)(araw.x >> 16),
                           (ushortT)(araw.y & 0xFFFF), (ushortT)(araw.y >> 16)};
    const int jrel = t * 32 + jh * 16 + lr;
    const float M1j = sMS[0][jrel], is1 = sMS[1][jrel];
    const float M2j = sMS[2][jrel], is2 = sMS[3][jrel];

    short w1v[4], w2v[4];
#pragma unroll
    for (int r = 0; r < 4; r++) {
      const float e = h2f(ev[r]);
      const float adj1v = bfdec(uu[r] & 0xFFFEu);
      const bool gon1 = (uu[r] & 0xFFFEu) != 0, gon2 = (uu[r] & 1u) != 0;
      w1v[r] = f2bf(gon1 ? __expf(e - M1j) * adj1v * is1 : 0.f);
      w2v[r] = f2bf(gon2 ? __expf(e - M2j) * is2 : 0.f);
    }
#pragma unroll
    for (int r = 0; r < 4; r++) {
      wlds[par][0][ih * 16 + kg * 4 + r][jh * 16 + lr] = w1v[r];
      wlds[par][1][ih * 16 + kg * 4 + r][jh * 16 + lr] = w2v[r];
    }
    __syncthreads();
#pragma unroll
    for (int m = 0; m < 2; m++) {
      bf16x8 af = *(const bf16x8*)&wlds[par][m][ih * 16 + lr][kg * 8];
#pragma unroll
      for (int q = 0; q < 3; q++)
        acc[m][q] = __builtin_amdgcn_mfma_f32_16x16x32_bf16(af, bt[q], acc[m][q], 0, 0, 0);
    }
    eraw = eN; araw = aN;
  }
  const int i0 = it * 32;
#pragma unroll
  for (int m = 0; m < 2; m++) {
#pragma unroll
    for (int q = 0; q < 3; q++) {
      const int dt = dbase + q;
      if (dt < 5) {
        ushortT* dst = (m ? hp2p : hp1p) +
            (((size_t)jc * B_ + b) * N_ + i0 + ih * 16 + kg * 4) * 80 + dt * 16 + lr;
#pragma unroll
        for (int r = 0; r < 4; r++) dst[(size_t)r * 80] = (ushortT)f2bf(acc[m][q][r]);
      }
    }
  }
}

// ------------- final-layer combine fused with masked pool (atomic into pooled)
__global__ __launch_bounds__(256) void combine_pool(
    const float* __restrict__ x,
    const ushortT* __restrict__ hp1p, const ushortT* __restrict__ hp2p, int JC,
    const float* __restrict__ g1, const float* __restrict__ g2w,
    const float* __restrict__ g2b,
    const float* __restrict__ V, float* __restrict__ pooled)
{
  const int r = blockIdx.x * 4 + (threadIdx.x >> 6);
  const int t = threadIdx.x & 63;
  __shared__ float sAcc[D_];
  if (threadIdx.x < D_) sAcc[threadIdx.x] = 0.f;
  __syncthreads();
  float s1a = 0.f, s2a = 0.f, s1b = 0.f, s2b = 0.f;
  for (int q = 0; q < JC; q++) {
    const size_t base = ((size_t)q * (B_ * N_) + r) * 80;
    s1a += bfdec(hp1p[base + t]);
    s2a += bfdec(hp2p[base + t]);
    if (t < D_ - 64) {
      s1b += bfdec(hp1p[base + 64 + t]);
      s2b += bfdec(hp2p[base + 64 + t]);
    }
  }
  const float a0 = fmaxf(s1a, 0.f), b0 = fmaxf(s2a, 0.f);
  const float a1v = fmaxf(s1b, 0.f), b1v = fmaxf(s2b, 0.f);
  const float* xr = x + (size_t)r * D_;
  const float x0 = xr[t];
  float d1 = x0 * g1[t], d2 = a0 * g2w[t], d3 = b0 * g2w[t];
  float x1 = 0.f;
  if (t < D_ - 64) {
    x1 = xr[64 + t];
    d1 += x1 * g1[64 + t]; d2 += a1v * g2w[64 + t]; d3 += b1v * g2w[64 + t];
  }
#pragma unroll
  for (int off = 1; off < 64; off <<= 1) {
    d1 += __shfl_xor(d1, off);
    d2 += __shfl_xor(d2, off);
    d3 += __shfl_xor(d3, off);
  }
  const float bb = g2b[0];
  const float c1 = 1.f / (1.f + __expf(-(d1 + d2 + bb)));
  const float c2 = 1.f / (1.f + __expf(-(d1 + d3 + bb)));
  const float Vr = V[r];
  const float o0 = (c1 * x0 + (1.f - c1) * a0) - (c2 * x0 + (1.f - c2) * b0);
  atomicAdd(&sAcc[t], o0 * Vr);
  if (t < D_ - 64) {
    const float o1 = (c1 * x1 + (1.f - c1) * a1v) - (c2 * x1 + (1.f - c2) * b1v);
    atomicAdd(&sAcc[64 + t], o1 * Vr);
  }
  __syncthreads();
  if (threadIdx.x < D_) {
    const int b = blockIdx.x >> 8;
    atomicAdd(&pooled[b * D_ + threadIdx.x], sAcc[threadIdx.x]);
  }
}

// ------------- MLP head: 8 blocks (one per batch row) x 1024 thr, 8-way sliced
__global__ __launch_bounds__(1024) void fc_kernel(
    const float* __restrict__ pooled,
    const float* __restrict__ w0, const float* __restrict__ b0,
    const float* __restrict__ w1, const float* __restrict__ b1,
    const float* __restrict__ w2, const float* __restrict__ b2,
    const float* __restrict__ w3, const float* __restrict__ b3,
    float* __restrict__ out)
{
  const int b = blockIdx.x;
  const int t = threadIdx.x;
  const int o = t >> 3, s = t & 7;
  __shared__ float pin[D_];
  __shared__ float part[DFC_][9];
  __shared__ float bufA[DFC_], bufB[DFC_];
  if (t < D_) pin[t] = pooled[b * D_ + t];
  __syncthreads();
  {
    float a = 0.f;
    const int m0 = s * 9, m1 = (m0 + 9 < D_) ? m0 + 9 : D_;
    for (int m = m0; m < m1; m++) a += pin[m] * w0[o * D_ + m];
    part[o][s] = a;
  }
  __syncthreads();
  if (t < DFC_) {
    float a = b0[t];
#pragma unroll
    for (int q = 0; q < 8; q++) a += part[t][q];
    bufA[t] = fmaxf(a, 0.f);
  }
  __syncthreads();
  {
    float a = 0.f;
    const float4* wr = (const float4*)(w1 + o * DFC_ + s * 16);
    const float4* br = (const float4*)&bufA[s * 16];
#pragma unroll
    for (int m4 = 0; m4 < 4; m4++) a += dot4(br[m4], wr[m4]);
    part[o][s] = a;
  }
  __syncthreads();
  if (t < DFC_) {
    float a = b1[t];
#pragma unroll
    for (int q = 0; q < 8; q++) a += part[t][q];
    bufB[t] = fmaxf(a, 0.f);
  }
  __syncthreads();
  {
    float a = 0.f;
    const float4* wr = (const float4*)(w2 + o * DFC_ + s * 16);
    const float4* br = (const float4*)&bufB[s * 16];
#pragma unroll
    for (int m4 = 0; m4 < 4; m4++) a += dot4(br[m4], wr[m4]);
    part[o][s] = a;
  }
  __syncthreads();
  if (t < DFC_) {
    float a = b2[t];
#pragma unroll
    for (int q = 0; q < 8; q++) a += part[t][q];
    bufA[t] = fmaxf(a, 0.f);
  }
  __syncthreads();
  if (t < 32) {
    const float4 wv = *(const float4*)(w3 + t * 4);
    const float4 bv = *(const float4*)&bufA[t * 4];
    float a = dot4(bv, wv);
    a += __shfl_xor(a, 1); a += __shfl_xor(a, 2); a += __shfl_xor(a, 4);
    a += __shfl_xor(a, 8); a += __shfl_xor(a, 16);
    if (t == 0) out[b] = 1.f / (1.f + __expf(-(a + b3[0])));
  }
}

// ----------------------------------------------------------------------
extern "C" void kernel_launch(void* const* d_in, const int* in_sizes, int n_in,
                              void* d_out, int out_size, void* d_ws, size_t ws_size,
                              hipStream_t stream)
{
  const float* H     = (const float*)d_in[0];
  const float* A1    = (const float*)d_in[1];
  const float* A2    = (const float*)d_in[2];
  const float* V     = (const float*)d_in[3];
  const float* few   = (const float*)d_in[4];
  const float* mup   = (const float*)d_in[5];
  const float* devp  = (const float*)d_in[6];
  const float* gW    = (const float*)d_in[7];
  const float* gA    = (const float*)d_in[8];
  const float* g1    = (const float*)d_in[9];
  const float* g2w   = (const float*)d_in[10];
  const float* g2b   = (const float*)d_in[11];
  const float* w0 = (const float*)d_in[12]; const float* b0 = (const float*)d_in[13];
  const float* w1 = (const float*)d_in[14]; const float* b1 = (const float*)d_in[15];
  const float* w2 = (const float*)d_in[16]; const float* b2 = (const float*)d_in[17];
  const float* w3 = (const float*)d_in[18]; const float* b3 = (const float*)d_in[19];
  float* outp = (float*)d_out;

  float* ws = (float*)d_ws;
  // fixed layout (float offsets)
  float*   x      = ws;                         // 573440
  short*   hb16   = (short*)(ws + 573440);
  short*   hAb16  = (short*)(ws + 966656);
  short*   hT16   = (short*)(ws + 1359872);
  short*   Wb16   = (short*)(ws + 1753088);
  short*   Atb16  = (short*)(ws + 1768448);
  short*   fewb16 = (short*)(ws + 1783808);     // 80*64 bf16 -> 1786368
  float*   M1p    = ws + 1786368;               // 8*B*N each
  float*   S1p    = ws + 1851904;
  float*   M2p    = ws + 1917440;
  float*   S2p    = ws + 1982976;
  float*   pooled = ws + 2048512;               // -> 2049088
  ushortT* adj_t  = (ushortT*)(ws + 2049088);   // 8M u16 -> 6243392
  ushortT* Et     = (ushortT*)(ws + 6243392);   // 8M u16 -> 10437696
  const int JC = 4;                              // = 32 / NJT
  ushortT* hp1p   = (ushortT*)(ws + 10437696);
  ushortT* hp2p   = hp1p + (size_t)JC * 655360u;
  const size_t need = (size_t)10437696u * 4u + (size_t)JC * 655360u * 4u;
  if (ws_size < need) return;
  const int ROWS = B_ * N_;

  prep_all<<<32 * 32 * B_ + 17, 256, 0, stream>>>(A1, A2, mup, devp, gW, gA, few,
      adj_t, Wb16, Atb16, fewb16, hT16, pooled);

  for (int k = 0; k < 4; k++) {
    const short* Wk  = Wb16  + (size_t)k * 80 * 96;
    const short* Atk = Atb16 + (size_t)k * 80 * 96;
    if (k == 0)
      gatmm_mfma<0><<<ROWS / GR, 128, 0, stream>>>(
          x, H, fewb16, nullptr, nullptr, 0, nullptr, nullptr, nullptr,
          Wk, Atk, hb16, hAb16, hT16);
    else
      gatmm_mfma<1><<<ROWS / GR, 128, 0, stream>>>(
          x, nullptr, nullptr, hp1p, hp2p, JC,
          g1 + (size_t)(k - 1) * D_, g2w + (size_t)(k - 1) * D_, g2b + (k - 1),
          Wk, Atk, hb16, hAb16, hT16);
    passE_mfma<<<dim3(32, 8, B_), 256, 0, stream>>>(adj_t, hb16, hAb16, Et,
                                                    M1p, S1p, M2p, S2p);
    passPV_mfma<<<dim3(32, JC, B_), 256, 0, stream>>>(adj_t, Et, hT16,
        M1p, S1p, M2p, S2p, hp1p, hp2p);
  }
  combine_pool<<<ROWS / 4, 256, 0, stream>>>(x, hp1p, hp2p, JC,
      g1 + 3 * D_, g2w + 3 * D_, g2b + 3, V, pooled);
  fc_kernel<<<B_, 1024, 0, stream>>>(pooled, w0, b0, w1, b1, w2, b2, w3, b3, outp);
}

// Round 16
// 247.821 us; speedup vs baseline: 1.1159x; 1.0247x over previous
//
#include <hip/hip_runtime.h>

#define B_   8
#define N_   1024
#define F0_  56
#define D_   70
#define DK_  96      // bf16 K-padded row stride (3 x 32)
#define DFC_ 128

typedef __attribute__((ext_vector_type(8))) short bf16x8;
typedef __attribute__((ext_vector_type(4))) float f32x4;
typedef unsigned short ushortT;
typedef _Float16 f16T;

__device__ __forceinline__ short f2bf(float x) {
  unsigned u = __builtin_bit_cast(unsigned, x);
  u += 0x7FFF + ((u >> 16) & 1);
  return (short)(u >> 16);
}
__device__ __forceinline__ float bfdec(unsigned u16bits) {
  unsigned v = u16bits << 16;
  return __builtin_bit_cast(float, v);
}
__device__ __forceinline__ ushortT f2h(float x) {
  f16T h = (f16T)x; return __builtin_bit_cast(ushortT, h);
}
__device__ __forceinline__ float h2f(ushortT u) {
  return (float)__builtin_bit_cast(f16T, u);
}
__device__ __forceinline__ float dot4(float4 a, float4 b) {
  return a.x * b.x + a.y * b.y + a.z * b.z + a.w * b.w;
}

// ---- prep_all: adj tiles (8192 blocks) | weights | hT pad | few | pooled=0
__global__ __launch_bounds__(256) void prep_all(
    const float* __restrict__ A1, const float* __restrict__ A2,
    const float* __restrict__ mup, const float* __restrict__ devp,
    const float* __restrict__ gW, const float* __restrict__ gA,
    const float* __restrict__ few,
    ushortT* __restrict__ adj_t,
    short* __restrict__ Wb16, short* __restrict__ Atb16, short* __restrict__ fewb16,
    short* __restrict__ hT, float* __restrict__ pooled)
{
  const int bid = blockIdx.x;
  const int tid = threadIdx.x;
  if (bid >= 32 * 32 * B_) {
    const int e = bid - 32 * 32 * B_;
    if (e < 8) {
      const int k = e & 3;
      const bool isW = e < 4;
      short* dst = (isW ? Wb16 : Atb16) + (size_t)k * 80 * 96;
      const float* src = (isW ? gW : gA) + (size_t)k * D_ * D_;
      for (int i = tid; i < 80 * 96; i += 256) {
        const int d = i / 96, m = i - (i / 96) * 96;
        float v = 0.f;
        if (d < D_ && m < D_) v = isW ? src[d * D_ + m] : src[m * D_ + d];
        dst[i] = f2bf(v);
      }
    } else if (e < 16) {
      const int b = e - 8;
      uint2* p = (uint2*)(hT + ((size_t)(b * 96 + 80)) * N_);
      for (int i = tid; i < 16 * N_ / 4; i += 256) p[i] = (uint2){0, 0};
    } else {
      for (int i = tid; i < 80 * 64; i += 256) {
        const int d = i >> 6, m = i & 63;
        fewb16[i] = f2bf((d < D_ && m < F0_) ? few[d * F0_ + m] : 0.f);
      }
      for (int i = tid; i < B_ * D_; i += 256) pooled[i] = 0.f;
    }
    return;
  }
  const int it = bid & 31, jt = (bid >> 5) & 31, b = bid >> 10;
  const int i0 = it * 32, j0 = jt * 32;
  const int jrel = tid >> 3, iq = tid & 7;
  const float mu = mup[0], idev = 1.0f / devp[0];
  const size_t base = ((size_t)b * N_ + j0 + jrel) * N_ + i0 + iq * 4;
  const float4 a1 = *(const float4*)(A1 + base);
  const float4 a2 = *(const float4*)(A2 + base);
  const float a1v[4] = {a1.x, a1.y, a1.z, a1.w};
  const float a2v[4] = {a2.x, a2.y, a2.z, a2.w};
  ushortT o[4];
#pragma unroll
  for (int k = 0; k < 4; k++) {
    const float rbf = (a2v[k] <= 10.f) ? __expf(-(a2v[k] - mu) * (a2v[k] - mu) * idev) : 0.f;
    const float adj1 = rbf + a1v[k];
    ushortT u = ((ushortT)f2bf(adj1)) & 0xFFFE;
    if (a1v[k] > 0.f) u |= 1;
    o[k] = u;
  }
  *(uint2*)(adj_t + ((size_t)(b * 32 + jt) * 32 + it) * 1024 + jrel * 32 + iq * 4) =
      *(uint2*)o;
}

// -- fused [featem|combine] + h + hA + hT via MFMA (16 rows, 2 waves, nt-split)
#define GR 16
template<int MODE>
__global__ __launch_bounds__(128) void gatmm_mfma(
    float* __restrict__ x, const float* __restrict__ H, const short* __restrict__ fewb,
    const ushortT* __restrict__ hp1p, const ushortT* __restrict__ hp2p, int JC,
    const float* __restrict__ g1, const float* __restrict__ g2w, const float* __restrict__ g2b,
    const short* __restrict__ Wb, const short* __restrict__ Atb,
    short* __restrict__ hb16, short* __restrict__ hAb16, short* __restrict__ hT)
{
  const int tid = threadIdx.x;
  const int w = tid >> 6, lane = tid & 63;
  const int lr = lane & 15, kg = lane >> 4;
  const int r0 = blockIdx.x * GR;
  const int b = r0 >> 10, n0 = r0 & (N_ - 1);

  __shared__ __align__(16) short sxb[GR][104];
  __shared__ __align__(16) short shl[GR][104];

  for (int i = tid; i < 160; i += 128) {
    const int r = i / 10, c = i - (i / 10) * 10;
    *(uint2*)&sxb[r][64 + c * 4] = (uint2){0, 0};
    *(uint2*)&shl[r][64 + c * 4] = (uint2){0, 0};
  }

  if (MODE == 0) {
    for (int i = tid; i < GR * 64; i += 128) {
      const int r = i >> 6, c = i & 63;
      shl[r][c] = f2bf((c < F0_) ? H[(size_t)(r0 + r) * F0_ + c] : 0.f);
    }
    __syncthreads();
    bf16x8 hf[2];
#pragma unroll
    for (int ks = 0; ks < 2; ks++)
      hf[ks] = *(const bf16x8*)&shl[lr][ks * 32 + kg * 8];
    for (int nt = w; nt < 5; nt += 2) {
      f32x4 accf = (f32x4){0.f, 0.f, 0.f, 0.f};
#pragma unroll
      for (int ks = 0; ks < 2; ks++) {
        bf16x8 bw = *(const bf16x8*)(fewb + (size_t)(nt * 16 + lr) * 64 + ks * 32 + kg * 8);
        accf = __builtin_amdgcn_mfma_f32_16x16x32_bf16(hf[ks], bw, accf, 0, 0, 0);
      }
#pragma unroll
      for (int r = 0; r < 4; r++) {
        const int i = kg * 4 + r, d = nt * 16 + lr;
        if (d < D_) x[(size_t)(r0 + i) * D_ + d] = accf[r];
        sxb[i][d] = f2bf(accf[r]);
      }
    }
  } else {
    const int lt = tid & 15, gg = tid >> 4;
#pragma unroll
    for (int rg = 0; rg < 2; rg++) {
      const int row = gg * 2 + rg;
      const int grow = r0 + row;
      float s1[5], s2[5], xv[5];
#pragma unroll
      for (int q = 0; q < 5; q++) { s1[q] = 0.f; s2[q] = 0.f; xv[q] = 0.f; }
      for (int jc = 0; jc < JC; jc++) {
        const size_t bp = ((size_t)jc * (B_ * N_) + grow) * 80 + lt;
#pragma unroll
        for (int q = 0; q < 5; q++) {
          s1[q] += bfdec(hp1p[bp + 16 * q]);
          s2[q] += bfdec(hp2p[bp + 16 * q]);
        }
      }
      float d1 = 0.f, d2 = 0.f, d3 = 0.f;
#pragma unroll
      for (int q = 0; q < 5; q++) {
        const int d = lt + 16 * q;
        if (d < D_) {
          s1[q] = fmaxf(s1[q], 0.f); s2[q] = fmaxf(s2[q], 0.f);
          xv[q] = x[(size_t)grow * D_ + d];
          d1 += xv[q] * g1[d]; d2 += s1[q] * g2w[d]; d3 += s2[q] * g2w[d];
        }
      }
#pragma unroll
      for (int off = 1; off < 16; off <<= 1) {
        d1 += __shfl_xor(d1, off); d2 += __shfl_xor(d2, off); d3 += __shfl_xor(d3, off);
      }
      const float bb = g2b[0];
      const float c1 = 1.f / (1.f + __expf(-(d1 + d2 + bb)));
      const float c2 = 1.f / (1.f + __expf(-(d1 + d3 + bb)));
#pragma unroll
      for (int q = 0; q < 5; q++) {
        const int d = lt + 16 * q;
        if (d < D_) {
          const float xn = (c1 * xv[q] + (1.f - c1) * s1[q]) - (c2 * xv[q] + (1.f - c2) * s2[q]);
          x[(size_t)grow * D_ + d] = xn;
          sxb[row][d] = f2bf(xn);
        }
      }
    }
  }
  __syncthreads();

  // GEMM1: h = x @ W^T
  bf16x8 af[3];
#pragma unroll
  for (int ks = 0; ks < 3; ks++)
    af[ks] = *(const bf16x8*)&sxb[lr][ks * 32 + kg * 8];
  for (int nt = w; nt < 5; nt += 2) {
    f32x4 acc = (f32x4){0.f, 0.f, 0.f, 0.f};
#pragma unroll
    for (int ks = 0; ks < 3; ks++) {
      bf16x8 bw = *(const bf16x8*)(Wb + (size_t)(nt * 16 + lr) * 96 + ks * 32 + kg * 8);
      acc = __builtin_amdgcn_mfma_f32_16x16x32_bf16(af[ks], bw, acc, 0, 0, 0);
    }
#pragma unroll
    for (int r = 0; r < 4; r++)
      shl[kg * 4 + r][nt * 16 + lr] = f2bf(acc[r]);
  }
  __syncthreads();

  for (int i = tid; i < GR * 12; i += 128) {
    const int r = i / 12, seg = i - (i / 12) * 12;
    *(bf16x8*)(hb16 + (size_t)(r0 + r) * DK_ + seg * 8) = *(const bf16x8*)&shl[r][seg * 8];
  }
  for (int i = tid; i < 160; i += 128) {
    const int d = i >> 1, ng = i & 1;
    short tmp[8];
#pragma unroll
    for (int k = 0; k < 8; k++) tmp[k] = shl[ng * 8 + k][d];
    *(bf16x8*)(hT + ((size_t)(b * 96 + d)) * N_ + n0 + ng * 8) = *(bf16x8*)tmp;
  }

  // GEMM2: hA = h @ A
  bf16x8 ah[3];
#pragma unroll
  for (int ks = 0; ks < 3; ks++)
    ah[ks] = *(const bf16x8*)&shl[lr][ks * 32 + kg * 8];
  for (int nt = w; nt < 5; nt += 2) {
    f32x4 acc2 = (f32x4){0.f, 0.f, 0.f, 0.f};
#pragma unroll
    for (int ks = 0; ks < 3; ks++) {
      bf16x8 bw = *(const bf16x8*)(Atb + (size_t)(nt * 16 + lr) * 96 + ks * 32 + kg * 8);
      acc2 = __builtin_amdgcn_mfma_f32_16x16x32_bf16(ah[ks], bw, acc2, 0, 0, 0);
    }
#pragma unroll
    for (int r = 0; r < 4; r++)
      sxb[kg * 4 + r][nt * 16 + lr] = f2bf(acc2[r]);
  }
  __syncthreads();
  for (int i = tid; i < GR * 12; i += 128) {
    const int r = i / 12, seg = i - (i / 12) * 12;
    *(bf16x8*)(hAb16 + (size_t)(r0 + r) * DK_ + seg * 8) = *(const bf16x8*)&sxb[r][seg * 8];
  }
}

// ---------------- passE: E tiles fp16 + SHARED-REFERENCE masked softmax stats
// gate2 (A1 edge) is a subset of gate1 (adj>0): both sums share max M over gate1.
// S2 stored referenced to M1 (S2ref); passPV uses w2 = exp(e-M1)/S2ref.
__global__ __launch_bounds__(256) void passE_mfma(
    const ushortT* __restrict__ adj_t,
    const short* __restrict__ hb16, const short* __restrict__ hAb16,
    ushortT* __restrict__ Et,
    float* __restrict__ M1p, float* __restrict__ S1p, float* __restrict__ S2p)
{
  const int jt = blockIdx.x, ic = blockIdx.y, b = blockIdx.z;
  const int tid = threadIdx.x, w = tid >> 6, lane = tid & 63;
  const int lr = lane & 15, kg = lane >> 4;
  const int ih = w >> 1, jh = w & 1;
  const int j0 = jt * 32;
  const short* hb  = hb16  + (size_t)b * N_ * DK_;
  const short* hAb = hAb16 + (size_t)b * N_ * DK_;

  bf16x8 b_h[3], b_hA[3];
  {
    const short* p = hb  + (size_t)(j0 + jh * 16 + lr) * DK_ + kg * 8;
    const short* q = hAb + (size_t)(j0 + jh * 16 + lr) * DK_ + kg * 8;
#pragma unroll
    for (int ks = 0; ks < 3; ks++) {
      b_h[ks]  = *(const bf16x8*)(p + ks * 32);
      b_hA[ks] = *(const bf16x8*)(q + ks * 32);
    }
  }
  const int i0base = ic * 128;
  const int lofs = (jh * 16 + lr) * 32 + (ih * 16 + kg * 4);
  float Ev[16];
  unsigned g1m = 0, g2m = 0;

#pragma unroll
  for (int iter = 0; iter < 4; iter++) {
    const int i0 = i0base + iter * 32 + ih * 16;
    const short* pa = hAb + (size_t)(i0 + lr) * DK_ + kg * 8;
    const short* ph = hb  + (size_t)(i0 + lr) * DK_ + kg * 8;
    bf16x8 a_hA[3], a_h[3];
#pragma unroll
    for (int ks = 0; ks < 3; ks++) {
      a_hA[ks] = *(const bf16x8*)(pa + ks * 32);
      a_h[ks]  = *(const bf16x8*)(ph + ks * 32);
    }
    const int itg = ic * 4 + iter;
    const size_t tb = ((size_t)(b * 32 + jt) * 32 + itg) * 1024 + lofs;
    const uint2 araw = *(const uint2*)(adj_t + tb);
    f32x4 E = {0.f, 0.f, 0.f, 0.f};
#pragma unroll
    for (int ks = 0; ks < 3; ks++)
      E = __builtin_amdgcn_mfma_f32_16x16x32_bf16(a_hA[ks], b_h[ks], E, 0, 0, 0);
#pragma unroll
    for (int ks = 0; ks < 3; ks++)
      E = __builtin_amdgcn_mfma_f32_16x16x32_bf16(a_h[ks], b_hA[ks], E, 0, 0, 0);
    ushortT ev16[4];
#pragma unroll
    for (int r = 0; r < 4; r++) ev16[r] = f2h(E[r]);
    {
      const unsigned lo = (unsigned)ev16[0] | ((unsigned)ev16[1] << 16);
      const unsigned hi = (unsigned)ev16[2] | ((unsigned)ev16[3] << 16);
      *(uint2*)(Et + tb) = (uint2){lo, hi};
    }
    const ushortT uu[4] = {(ushortT)(araw.x & 0xFFFF), (ushortT)(araw.x >> 16),
                           (ushortT)(araw.y & 0xFFFF), (ushortT)(araw.y >> 16)};
#pragma unroll
    for (int r = 0; r < 4; r++) {
      Ev[iter * 4 + r] = h2f(ev16[r]);
      g1m |= ((uu[r] & 0xFFFEu) ? 1u : 0u) << (iter * 4 + r);
      g2m |= (unsigned)(uu[r] & 1u) << (iter * 4 + r);
    }
  }
  // shared-reference stats: M over gate1; one exp table for both sums
  float M1r = -3.0e38f;
#pragma unroll
  for (int k = 0; k < 16; k++)
    M1r = ((g1m >> k) & 1u) ? fmaxf(M1r, Ev[k]) : M1r;
  float S1r = 0.f, S2r = 0.f;
#pragma unroll
  for (int k = 0; k < 16; k++) {
    const float t = __expf(Ev[k] - M1r);
    S1r += ((g1m >> k) & 1u) ? t : 0.f;
    S2r += ((g2m >> k) & 1u) ? t : 0.f;
  }
#pragma unroll
  for (int off = 16; off <= 32; off <<= 1) {
    const float Mo = __shfl_xor(M1r, off);
    const float S1o = __shfl_xor(S1r, off);
    const float S2o = __shfl_xor(S2r, off);
    const float nM = fmaxf(M1r, Mo);
    const float fa = __expf(M1r - nM), fb = __expf(Mo - nM);
    S1r = S1r * fa + S1o * fb;
    S2r = S2r * fa + S2o * fb;
    M1r = nM;
  }
  __shared__ float sM[4][16], sS1[4][16], sS2[4][16];
  if (lane < 16) { sM[w][lr] = M1r; sS1[w][lr] = S1r; sS2[w][lr] = S2r; }
  __syncthreads();
  if (tid < 32) {
    const int jhh = tid >> 4, l2 = tid & 15;
    const float Ma = sM[jhh][l2], Mb = sM[2 + jhh][l2];
    const float nM = fmaxf(Ma, Mb);
    const float fa = __expf(Ma - nM), fb = __expf(Mb - nM);
    const size_t o = ((size_t)b * 8 + ic) * N_ + j0 + jhh * 16 + l2;
    M1p[o] = nM;
    S1p[o] = sS1[jhh][l2] * fa + sS1[2 + jhh][l2] * fb;
    S2p[o] = sS2[jhh][l2] * fa + sS2[2 + jhh][l2] * fb;
  }
}

// --------------------- passPV: prefetched E/adj tiles, weights, PV MFMA
#define NJT 8
__global__ __launch_bounds__(256) void passPV_mfma(
    const ushortT* __restrict__ adj_t, const ushortT* __restrict__ Et,
    const short* __restrict__ hT16,
    const float* __restrict__ M1p, const float* __restrict__ S1p,
    const float* __restrict__ S2p,
    ushortT* __restrict__ hp1p, ushortT* __restrict__ hp2p)
{
  const int it = blockIdx.x, jc = blockIdx.y, b = blockIdx.z;
  const int tid = threadIdx.x, w = tid >> 6, lane = tid & 63;
  const int lr = lane & 15, kg = lane >> 4;
  const int ih = w >> 1, jh = w & 1;
  const int dbase = (w & 1) * 3;
  const int jbase = jc * NJT * 32;
  const int lofs = (jh * 16 + lr) * 32 + (ih * 16 + kg * 4);

  __shared__ float sMS[3][NJT * 32];
  for (int idx = tid; idx < NJT * 32; idx += 256) {
    const int col = jbase + idx;
    float Mv[8];
    float M = -3.0e38f;
#pragma unroll
    for (int q = 0; q < 8; q++) {
      Mv[q] = M1p[((size_t)b * 8 + q) * N_ + col];
      M = fmaxf(M, Mv[q]);
    }
    float S1 = 0.f, S2 = 0.f;
#pragma unroll
    for (int q = 0; q < 8; q++) {
      const float f = __expf(Mv[q] - M);
      S1 += S1p[((size_t)b * 8 + q) * N_ + col] * f;
      S2 += S2p[((size_t)b * 8 + q) * N_ + col] * f;
    }
    sMS[0][idx] = M; sMS[1][idx] = 1.0f / S1; sMS[2][idx] = 1.0f / S2;
  }

  const short* hTb = hT16 + (size_t)b * DK_ * N_;
  f32x4 acc[2][3];
#pragma unroll
  for (int m = 0; m < 2; m++)
#pragma unroll
    for (int q = 0; q < 3; q++) acc[m][q] = (f32x4){0.f, 0.f, 0.f, 0.f};

  __shared__ short wlds[2][2][32][40];
  __syncthreads();

  size_t tb = ((size_t)(b * 32 + jc * NJT) * 32 + it) * 1024 + lofs;
  uint2 eraw = *(const uint2*)(Et + tb);
  uint2 araw = *(const uint2*)(adj_t + tb);

#pragma unroll
  for (int t = 0; t < NJT; ++t) {
    const int j0 = jbase + t * 32;
    const int par = t & 1;
    bf16x8 bt[3];
#pragma unroll
    for (int q = 0; q < 3; q++)
      bt[q] = *(const bf16x8*)(hTb + (size_t)((dbase + q) * 16 + lr) * N_ + j0 + kg * 8);
    uint2 eN, aN;
    if (t + 1 < NJT) {
      const size_t tbn = ((size_t)(b * 32 + jc * NJT + t + 1) * 32 + it) * 1024 + lofs;
      eN = *(const uint2*)(Et + tbn);
      aN = *(const uint2*)(adj_t + tbn);
    }

    const ushortT ev[4] = {(ushortT)(eraw.x & 0xFFFF), (ushortT)(eraw.x >> 16),
                           (ushortT)(eraw.y & 0xFFFF), (ushortT)(eraw.y >> 16)};
    const ushortT uu[4] = {(ushortT)(araw.x & 0xFFFF), (ushortT)(araw.x >> 16),
                           (ushortT)(araw.y & 0xFFFF), (ushortT)(araw.y >> 16)};
    const int jrel = t * 32 + jh * 16 + lr;
    const float M1j = sMS[0][jrel], is1 = sMS[1][jrel], is2 = sMS[2][jrel];

    short w1v[4], w2v[4];
#pragma unroll
    for (int r = 0; r < 4; r++) {
      const float e = h2f(ev[r]);
      const float ex = __expf(e - M1j);          // shared for both masks
      const float adj1v = bfdec(uu[r] & 0xFFFEu);
      w1v[r] = f2bf((uu[r] & 0xFFFEu) ? ex * adj1v * is1 : 0.f);
      w2v[r] = f2bf((uu[r] & 1u) ? ex * is2 : 0.f);
    }
#pragma unroll
    for (int r = 0; r < 4; r++) {
      wlds[par][0][ih * 16 + kg * 4 + r][jh * 16 + lr] = w1v[r];
      wlds[par][1][ih * 16 + kg * 4 + r][jh * 16 + lr] = w2v[r];
    }
    __syncthreads();
#pragma unroll
    for (int m = 0; m < 2; m++) {
      bf16x8 af = *(const bf16x8*)&wlds[par][m][ih * 16 + lr][kg * 8];
#pragma unroll
      for (int q = 0; q < 3; q++)
        acc[m][q] = __builtin_amdgcn_mfma_f32_16x16x32_bf16(af, bt[q], acc[m][q], 0, 0, 0);
    }
    eraw = eN; araw = aN;
  }
  const int i0 = it * 32;
#pragma unroll
  for (int m = 0; m < 2; m++) {
#pragma unroll
    for (int q = 0; q < 3; q++) {
      const int dt = dbase + q;
      if (dt < 5) {
        ushortT* dst = (m ? hp2p : hp1p) +
            (((size_t)jc * B_ + b) * N_ + i0 + ih * 16 + kg * 4) * 80 + dt * 16 + lr;
#pragma unroll
        for (int r = 0; r < 4; r++) dst[(size_t)r * 80] = (ushortT)f2bf(acc[m][q][r]);
      }
    }
  }
}

// ------------- final-layer combine fused with masked pool (atomic into pooled)
__global__ __launch_bounds__(256) void combine_pool(
    const float* __restrict__ x,
    const ushortT* __restrict__ hp1p, const ushortT* __restrict__ hp2p, int JC,
    const float* __restrict__ g1, const float* __restrict__ g2w,
    const float* __restrict__ g2b,
    const float* __restrict__ V, float* __restrict__ pooled)
{
  const int r = blockIdx.x * 4 + (threadIdx.x >> 6);
  const int t = threadIdx.x & 63;
  __shared__ float sAcc[D_];
  if (threadIdx.x < D_) sAcc[threadIdx.x] = 0.f;
  __syncthreads();
  float s1a = 0.f, s2a = 0.f, s1b = 0.f, s2b = 0.f;
  for (int q = 0; q < JC; q++) {
    const size_t base = ((size_t)q * (B_ * N_) + r) * 80;
    s1a += bfdec(hp1p[base + t]);
    s2a += bfdec(hp2p[base + t]);
    if (t < D_ - 64) {
      s1b += bfdec(hp1p[base + 64 + t]);
      s2b += bfdec(hp2p[base + 64 + t]);
    }
  }
  const float a0 = fmaxf(s1a, 0.f), b0 = fmaxf(s2a, 0.f);
  const float a1v = fmaxf(s1b, 0.f), b1v = fmaxf(s2b, 0.f);
  const float* xr = x + (size_t)r * D_;
  const float x0 = xr[t];
  float d1 = x0 * g1[t], d2 = a0 * g2w[t], d3 = b0 * g2w[t];
  float x1 = 0.f;
  if (t < D_ - 64) {
    x1 = xr[64 + t];
    d1 += x1 * g1[64 + t]; d2 += a1v * g2w[64 + t]; d3 += b1v * g2w[64 + t];
  }
#pragma unroll
  for (int off = 1; off < 64; off <<= 1) {
    d1 += __shfl_xor(d1, off);
    d2 += __shfl_xor(d2, off);
    d3 += __shfl_xor(d3, off);
  }
  const float bb = g2b[0];
  const float c1 = 1.f / (1.f + __expf(-(d1 + d2 + bb)));
  const float c2 = 1.f / (1.f + __expf(-(d1 + d3 + bb)));
  const float Vr = V[r];
  const float o0 = (c1 * x0 + (1.f - c1) * a0) - (c2 * x0 + (1.f - c2) * b0);
  atomicAdd(&sAcc[t], o0 * Vr);
  if (t < D_ - 64) {
    const float o1 = (c1 * x1 + (1.f - c1) * a1v) - (c2 * x1 + (1.f - c2) * b1v);
    atomicAdd(&sAcc[64 + t], o1 * Vr);
  }
  __syncthreads();
  if (threadIdx.x < D_) {
    const int b = blockIdx.x >> 8;
    atomicAdd(&pooled[b * D_ + threadIdx.x], sAcc[threadIdx.x]);
  }
}

// ------------- MLP head: 8 blocks (one per batch row) x 1024 thr, 8-way sliced
__global__ __launch_bounds__(1024) void fc_kernel(
    const float* __restrict__ pooled,
    const float* __restrict__ w0, const float* __restrict__ b0,
    const float* __restrict__ w1, const float* __restrict__ b1,
    const float* __restrict__ w2, const float* __restrict__ b2,
    const float* __restrict__ w3, const float* __restrict__ b3,
    float* __restrict__ out)
{
  const int b = blockIdx.x;
  const int t = threadIdx.x;
  const int o = t >> 3, s = t & 7;
  __shared__ float pin[D_];
  __shared__ float part[DFC_][9];
  __shared__ float bufA[DFC_], bufB[DFC_];
  if (t < D_) pin[t] = pooled[b * D_ + t];
  __syncthreads();
  {
    float a = 0.f;
    const int m0 = s * 9, m1 = (m0 + 9 < D_) ? m0 + 9 : D_;
    for (int m = m0; m < m1; m++) a += pin[m] * w0[o * D_ + m];
    part[o][s] = a;
  }
  __syncthreads();
  if (t < DFC_) {
    float a = b0[t];
#pragma unroll
    for (int q = 0; q < 8; q++) a += part[t][q];
    bufA[t] = fmaxf(a, 0.f);
  }
  __syncthreads();
  {
    float a = 0.f;
    const float4* wr = (const float4*)(w1 + o * DFC_ + s * 16);
    const float4* br = (const float4*)&bufA[s * 16];
#pragma unroll
    for (int m4 = 0; m4 < 4; m4++) a += dot4(br[m4], wr[m4]);
    part[o][s] = a;
  }
  __syncthreads();
  if (t < DFC_) {
    float a = b1[t];
#pragma unroll
    for (int q = 0; q < 8; q++) a += part[t][q];
    bufB[t] = fmaxf(a, 0.f);
  }
  __syncthreads();
  {
    float a = 0.f;
    const float4* wr = (const float4*)(w2 + o * DFC_ + s * 16);
    const float4* br = (const float4*)&bufB[s * 16];
#pragma unroll
    for (int m4 = 0; m4 < 4; m4++) a += dot4(br[m4], wr[m4]);
    part[o][s] = a;
  }
  __syncthreads();
  if (t < DFC_) {
    float a = b2[t];
#pragma unroll
    for (int q = 0; q < 8; q++) a += part[t][q];
    bufA[t] = fmaxf(a, 0.f);
  }
  __syncthreads();
  if (t < 32) {
    const float4 wv = *(const float4*)(w3 + t * 4);
    const float4 bv = *(const float4*)&bufA[t * 4];
    float a = dot4(bv, wv);
    a += __shfl_xor(a, 1); a += __shfl_xor(a, 2); a += __shfl_xor(a, 4);
    a += __shfl_xor(a, 8); a += __shfl_xor(a, 16);
    if (t == 0) out[b] = 1.f / (1.f + __expf(-(a + b3[0])));
  }
}

// ----------------------------------------------------------------------
extern "C" void kernel_launch(void* const* d_in, const int* in_sizes, int n_in,
                              void* d_out, int out_size, void* d_ws, size_t ws_size,
                              hipStream_t stream)
{
  const float* H     = (const float*)d_in[0];
  const float* A1    = (const float*)d_in[1];
  const float* A2    = (const float*)d_in[2];
  const float* V     = (const float*)d_in[3];
  const float* few   = (const float*)d_in[4];
  const float* mup   = (const float*)d_in[5];
  const float* devp  = (const float*)d_in[6];
  const float* gW    = (const float*)d_in[7];
  const float* gA    = (const float*)d_in[8];
  const float* g1    = (const float*)d_in[9];
  const float* g2w   = (const float*)d_in[10];
  const float* g2b   = (const float*)d_in[11];
  const float* w0 = (const float*)d_in[12]; const float* b0 = (const float*)d_in[13];
  const float* w1 = (const float*)d_in[14]; const float* b1 = (const float*)d_in[15];
  const float* w2 = (const float*)d_in[16]; const float* b2 = (const float*)d_in[17];
  const float* w3 = (const float*)d_in[18]; const float* b3 = (const float*)d_in[19];
  float* outp = (float*)d_out;

  float* ws = (float*)d_ws;
  // fixed layout (float offsets)
  float*   x      = ws;                         // 573440
  short*   hb16   = (short*)(ws + 573440);
  short*   hAb16  = (short*)(ws + 966656);
  short*   hT16   = (short*)(ws + 1359872);
  short*   Wb16   = (short*)(ws + 1753088);
  short*   Atb16  = (short*)(ws + 1768448);
  short*   fewb16 = (short*)(ws + 1783808);     // 80*64 bf16 -> 1786368
  float*   M1p    = ws + 1786368;               // 8*B*N each
  float*   S1p    = ws + 1851904;
  float*   S2p    = ws + 1917440;
  float*   pooled = ws + 2048512;               // -> 2049088
  ushortT* adj_t  = (ushortT*)(ws + 2049088);   // 8M u16 -> 6243392
  ushortT* Et     = (ushortT*)(ws + 6243392);   // 8M u16 -> 10437696
  const int JC = 4;                              // = 32 / NJT
  ushortT* hp1p   = (ushortT*)(ws + 10437696);
  ushortT* hp2p   = hp1p + (size_t)JC * 655360u;
  const size_t need = (size_t)10437696u * 4u + (size_t)JC * 655360u * 4u;
  if (ws_size < need) return;
  const int ROWS = B_ * N_;

  prep_all<<<32 * 32 * B_ + 17, 256, 0, stream>>>(A1, A2, mup, devp, gW, gA, few,
      adj_t, Wb16, Atb16, fewb16, hT16, pooled);

  for (int k = 0; k < 4; k++) {
    const short* Wk  = Wb16  + (size_t)k * 80 * 96;
    const short* Atk = Atb16 + (size_t)k * 80 * 96;
    if (k == 0)
      gatmm_mfma<0><<<ROWS / GR, 128, 0, stream>>>(
          x, H, fewb16, nullptr, nullptr, 0, nullptr, nullptr, nullptr,
          Wk, Atk, hb16, hAb16, hT16);
    else
      gatmm_mfma<1><<<ROWS / GR, 128, 0, stream>>>(
          x, nullptr, nullptr, hp1p, hp2p, JC,
          g1 + (size_t)(k - 1) * D_, g2w + (size_t)(k - 1) * D_, g2b + (k - 1),
          Wk, Atk, hb16, hAb16, hT16);
    passE_mfma<<<dim3(32, 8, B_), 256, 0, stream>>>(adj_t, hb16, hAb16, Et,
                                                    M1p, S1p, S2p);
    passPV_mfma<<<dim3(32, JC, B_), 256, 0, stream>>>(adj_t, Et, hT16,
        M1p, S1p, S2p, hp1p, hp2p);
  }
  combine_pool<<<ROWS / 4, 256, 0, stream>>>(x, hp1p, hp2p, JC,
      g1 + 3 * D_, g2w + 3 * D_, g2b + 3, V, pooled);
  fc_kernel<<<B_, 1024, 0, stream>>>(pooled, w0, b0, w1, b1, w2, b2, w3, b3, outp);
}

// Round 17
// 239.086 us; speedup vs baseline: 1.1567x; 1.0365x over previous
//
#include <hip/hip_runtime.h>

#define B_   8
#define N_   1024
#define F0_  56
#define D_   70
#define DK_  96      // bf16 K-padded row stride (3 x 32)
#define DFC_ 128

typedef __attribute__((ext_vector_type(8))) short bf16x8;
typedef __attribute__((ext_vector_type(4))) float f32x4;
typedef unsigned short ushortT;
typedef _Float16 f16T;

__device__ __forceinline__ short f2bf(float x) {
  unsigned u = __builtin_bit_cast(unsigned, x);
  u += 0x7FFF + ((u >> 16) & 1);
  return (short)(u >> 16);
}
__device__ __forceinline__ float bfdec(unsigned u16bits) {
  unsigned v = u16bits << 16;
  return __builtin_bit_cast(float, v);
}
__device__ __forceinline__ ushortT f2h(float x) {
  f16T h = (f16T)x; return __builtin_bit_cast(ushortT, h);
}
__device__ __forceinline__ float h2f(ushortT u) {
  return (float)__builtin_bit_cast(f16T, u);
}
__device__ __forceinline__ float dot4(float4 a, float4 b) {
  return a.x * b.x + a.y * b.y + a.z * b.z + a.w * b.w;
}

// ---- prep_all: adj tiles (8192 blocks) | weights | hT pad | few | pooled=0
__global__ __launch_bounds__(256) void prep_all(
    const float* __restrict__ A1, const float* __restrict__ A2,
    const float* __restrict__ mup, const float* __restrict__ devp,
    const float* __restrict__ gW, const float* __restrict__ gA,
    const float* __restrict__ few,
    ushortT* __restrict__ adj_t,
    short* __restrict__ Wb16, short* __restrict__ Atb16, short* __restrict__ fewb16,
    short* __restrict__ hT, float* __restrict__ pooled)
{
  const int bid = blockIdx.x;
  const int tid = threadIdx.x;
  if (bid >= 32 * 32 * B_) {
    const int e = bid - 32 * 32 * B_;
    if (e < 8) {
      const int k = e & 3;
      const bool isW = e < 4;
      short* dst = (isW ? Wb16 : Atb16) + (size_t)k * 80 * 96;
      const float* src = (isW ? gW : gA) + (size_t)k * D_ * D_;
      for (int i = tid; i < 80 * 96; i += 256) {
        const int d = i / 96, m = i - (i / 96) * 96;
        float v = 0.f;
        if (d < D_ && m < D_) v = isW ? src[d * D_ + m] : src[m * D_ + d];
        dst[i] = f2bf(v);
      }
    } else if (e < 16) {
      const int b = e - 8;
      uint2* p = (uint2*)(hT + ((size_t)(b * 96 + 80)) * N_);
      for (int i = tid; i < 16 * N_ / 4; i += 256) p[i] = (uint2){0, 0};
    } else {
      for (int i = tid; i < 80 * 64; i += 256) {
        const int d = i >> 6, m = i & 63;
        fewb16[i] = f2bf((d < D_ && m < F0_) ? few[d * F0_ + m] : 0.f);
      }
      for (int i = tid; i < B_ * D_; i += 256) pooled[i] = 0.f;
    }
    return;
  }
  const int it = bid & 31, jt = (bid >> 5) & 31, b = bid >> 10;
  const int i0 = it * 32, j0 = jt * 32;
  const int jrel = tid >> 3, iq = tid & 7;
  const float mu = mup[0], idev = 1.0f / devp[0];
  const size_t base = ((size_t)b * N_ + j0 + jrel) * N_ + i0 + iq * 4;
  const float4 a1 = *(const float4*)(A1 + base);
  const float4 a2 = *(const float4*)(A2 + base);
  const float a1v[4] = {a1.x, a1.y, a1.z, a1.w};
  const float a2v[4] = {a2.x, a2.y, a2.z, a2.w};
  ushortT o[4];
#pragma unroll
  for (int k = 0; k < 4; k++) {
    const float rbf = (a2v[k] <= 10.f) ? __expf(-(a2v[k] - mu) * (a2v[k] - mu) * idev) : 0.f;
    const float adj1 = rbf + a1v[k];
    ushortT u = ((ushortT)f2bf(adj1)) & 0xFFFE;
    if (a1v[k] > 0.f) u |= 1;
    o[k] = u;
  }
  *(uint2*)(adj_t + ((size_t)(b * 32 + jt) * 32 + it) * 1024 + jrel * 32 + iq * 4) =
      *(uint2*)o;
}

// -- fused [featem|combine] + h + hA + hT via MFMA (16 rows, 2 waves, nt-split)
#define GR 16
template<int MODE>
__global__ __launch_bounds__(128) void gatmm_mfma(
    float* __restrict__ x, const float* __restrict__ H, const short* __restrict__ fewb,
    const ushortT* __restrict__ hp1p, const ushortT* __restrict__ hp2p, int JC,
    const float* __restrict__ g1, const float* __restrict__ g2w, const float* __restrict__ g2b,
    const short* __restrict__ Wb, const short* __restrict__ Atb,
    short* __restrict__ hb16, short* __restrict__ hAb16, short* __restrict__ hT)
{
  const int tid = threadIdx.x;
  const int w = tid >> 6, lane = tid & 63;
  const int lr = lane & 15, kg = lane >> 4;
  const int r0 = blockIdx.x * GR;
  const int b = r0 >> 10, n0 = r0 & (N_ - 1);

  __shared__ __align__(16) short sxb[GR][104];
  __shared__ __align__(16) short shl[GR][104];

  for (int i = tid; i < 160; i += 128) {
    const int r = i / 10, c = i - (i / 10) * 10;
    *(uint2*)&sxb[r][64 + c * 4] = (uint2){0, 0};
    *(uint2*)&shl[r][64 + c * 4] = (uint2){0, 0};
  }

  if (MODE == 0) {
    for (int i = tid; i < GR * 64; i += 128) {
      const int r = i >> 6, c = i & 63;
      shl[r][c] = f2bf((c < F0_) ? H[(size_t)(r0 + r) * F0_ + c] : 0.f);
    }
    __syncthreads();
    bf16x8 hf[2];
#pragma unroll
    for (int ks = 0; ks < 2; ks++)
      hf[ks] = *(const bf16x8*)&shl[lr][ks * 32 + kg * 8];
    for (int nt = w; nt < 5; nt += 2) {
      f32x4 accf = (f32x4){0.f, 0.f, 0.f, 0.f};
#pragma unroll
      for (int ks = 0; ks < 2; ks++) {
        bf16x8 bw = *(const bf16x8*)(fewb + (size_t)(nt * 16 + lr) * 64 + ks * 32 + kg * 8);
        accf = __builtin_amdgcn_mfma_f32_16x16x32_bf16(hf[ks], bw, accf, 0, 0, 0);
      }
#pragma unroll
      for (int r = 0; r < 4; r++) {
        const int i = kg * 4 + r, d = nt * 16 + lr;
        if (d < D_) x[(size_t)(r0 + i) * D_ + d] = accf[r];
        sxb[i][d] = f2bf(accf[r]);
      }
    }
  } else {
    const int lt = tid & 15, gg = tid >> 4;
#pragma unroll
    for (int rg = 0; rg < 2; rg++) {
      const int row = gg * 2 + rg;
      const int grow = r0 + row;
      float s1[5], s2[5], xv[5];
#pragma unroll
      for (int q = 0; q < 5; q++) { s1[q] = 0.f; s2[q] = 0.f; xv[q] = 0.f; }
      for (int jc = 0; jc < JC; jc++) {
        const size_t bp = ((size_t)jc * (B_ * N_) + grow) * 80 + lt;
#pragma unroll
        for (int q = 0; q < 5; q++) {
          s1[q] += bfdec(hp1p[bp + 16 * q]);
          s2[q] += bfdec(hp2p[bp + 16 * q]);
        }
      }
      float d1 = 0.f, d2 = 0.f, d3 = 0.f;
#pragma unroll
      for (int q = 0; q < 5; q++) {
        const int d = lt + 16 * q;
        if (d < D_) {
          s1[q] = fmaxf(s1[q], 0.f); s2[q] = fmaxf(s2[q], 0.f);
          xv[q] = x[(size_t)grow * D_ + d];
          d1 += xv[q] * g1[d]; d2 += s1[q] * g2w[d]; d3 += s2[q] * g2w[d];
        }
      }
#pragma unroll
      for (int off = 1; off < 16; off <<= 1) {
        d1 += __shfl_xor(d1, off); d2 += __shfl_xor(d2, off); d3 += __shfl_xor(d3, off);
      }
      const float bb = g2b[0];
      const float c1 = 1.f / (1.f + __expf(-(d1 + d2 + bb)));
      const float c2 = 1.f / (1.f + __expf(-(d1 + d3 + bb)));
#pragma unroll
      for (int q = 0; q < 5; q++) {
        const int d = lt + 16 * q;
        if (d < D_) {
          const float xn = (c1 * xv[q] + (1.f - c1) * s1[q]) - (c2 * xv[q] + (1.f - c2) * s2[q]);
          x[(size_t)grow * D_ + d] = xn;
          sxb[row][d] = f2bf(xn);
        }
      }
    }
  }
  __syncthreads();

  // GEMM1: h = x @ W^T
  bf16x8 af[3];
#pragma unroll
  for (int ks = 0; ks < 3; ks++)
    af[ks] = *(const bf16x8*)&sxb[lr][ks * 32 + kg * 8];
  for (int nt = w; nt < 5; nt += 2) {
    f32x4 acc = (f32x4){0.f, 0.f, 0.f, 0.f};
#pragma unroll
    for (int ks = 0; ks < 3; ks++) {
      bf16x8 bw = *(const bf16x8*)(Wb + (size_t)(nt * 16 + lr) * 96 + ks * 32 + kg * 8);
      acc = __builtin_amdgcn_mfma_f32_16x16x32_bf16(af[ks], bw, acc, 0, 0, 0);
    }
#pragma unroll
    for (int r = 0; r < 4; r++)
      shl[kg * 4 + r][nt * 16 + lr] = f2bf(acc[r]);
  }
  __syncthreads();

  for (int i = tid; i < GR * 12; i += 128) {
    const int r = i / 12, seg = i - (i / 12) * 12;
    *(bf16x8*)(hb16 + (size_t)(r0 + r) * DK_ + seg * 8) = *(const bf16x8*)&shl[r][seg * 8];
  }
  for (int i = tid; i < 160; i += 128) {
    const int d = i >> 1, ng = i & 1;
    short tmp[8];
#pragma unroll
    for (int k = 0; k < 8; k++) tmp[k] = shl[ng * 8 + k][d];
    *(bf16x8*)(hT + ((size_t)(b * 96 + d)) * N_ + n0 + ng * 8) = *(bf16x8*)tmp;
  }

  // GEMM2: hA = h @ A
  bf16x8 ah[3];
#pragma unroll
  for (int ks = 0; ks < 3; ks++)
    ah[ks] = *(const bf16x8*)&shl[lr][ks * 32 + kg * 8];
  for (int nt = w; nt < 5; nt += 2) {
    f32x4 acc2 = (f32x4){0.f, 0.f, 0.f, 0.f};
#pragma unroll
    for (int ks = 0; ks < 3; ks++) {
      bf16x8 bw = *(const bf16x8*)(Atb + (size_t)(nt * 16 + lr) * 96 + ks * 32 + kg * 8);
      acc2 = __builtin_amdgcn_mfma_f32_16x16x32_bf16(ah[ks], bw, acc2, 0, 0, 0);
    }
#pragma unroll
    for (int r = 0; r < 4; r++)
      sxb[kg * 4 + r][nt * 16 + lr] = f2bf(acc2[r]);
  }
  __syncthreads();
  for (int i = tid; i < GR * 12; i += 128) {
    const int r = i / 12, seg = i - (i / 12) * 12;
    *(bf16x8*)(hAb16 + (size_t)(r0 + r) * DK_ + seg * 8) = *(const bf16x8*)&sxb[r][seg * 8];
  }
}

// ---------------- passE: E tiles fp16 + SHARED-REFERENCE masked softmax stats
// grid (32 jt, 4 ic, B): 256 i-rows per block, 2 chunks of 4 unrolled iters.
__global__ __launch_bounds__(256) void passE_mfma(
    const ushortT* __restrict__ adj_t,
    const short* __restrict__ hb16, const short* __restrict__ hAb16,
    ushortT* __restrict__ Et,
    float* __restrict__ M1p, float* __restrict__ S1p, float* __restrict__ S2p)
{
  const int jt = blockIdx.x, ic = blockIdx.y, b = blockIdx.z;
  const int tid = threadIdx.x, w = tid >> 6, lane = tid & 63;
  const int lr = lane & 15, kg = lane >> 4;
  const int ih = w >> 1, jh = w & 1;
  const int j0 = jt * 32;
  const short* hb  = hb16  + (size_t)b * N_ * DK_;
  const short* hAb = hAb16 + (size_t)b * N_ * DK_;

  bf16x8 b_h[3], b_hA[3];
  {
    const short* p = hb  + (size_t)(j0 + jh * 16 + lr) * DK_ + kg * 8;
    const short* q = hAb + (size_t)(j0 + jh * 16 + lr) * DK_ + kg * 8;
#pragma unroll
    for (int ks = 0; ks < 3; ks++) {
      b_h[ks]  = *(const bf16x8*)(p + ks * 32);
      b_hA[ks] = *(const bf16x8*)(q + ks * 32);
    }
  }
  const int lofs = (jh * 16 + lr) * 32 + (ih * 16 + kg * 4);
  float Mrun = -3.0e38f, S1run = 0.f, S2run = 0.f;

  for (int chunk = 0; chunk < 2; chunk++) {
    float Ev[16];
    unsigned g1m = 0, g2m = 0;
#pragma unroll
    for (int iter = 0; iter < 4; iter++) {
      const int itg = ic * 8 + chunk * 4 + iter;
      const int i0 = itg * 32 + ih * 16;
      const short* pa = hAb + (size_t)(i0 + lr) * DK_ + kg * 8;
      const short* ph = hb  + (size_t)(i0 + lr) * DK_ + kg * 8;
      bf16x8 a_hA[3], a_h[3];
#pragma unroll
      for (int ks = 0; ks < 3; ks++) {
        a_hA[ks] = *(const bf16x8*)(pa + ks * 32);
        a_h[ks]  = *(const bf16x8*)(ph + ks * 32);
      }
      const size_t tb = ((size_t)(b * 32 + jt) * 32 + itg) * 1024 + lofs;
      const uint2 araw = *(const uint2*)(adj_t + tb);
      f32x4 E = {0.f, 0.f, 0.f, 0.f};
#pragma unroll
      for (int ks = 0; ks < 3; ks++)
        E = __builtin_amdgcn_mfma_f32_16x16x32_bf16(a_hA[ks], b_h[ks], E, 0, 0, 0);
#pragma unroll
      for (int ks = 0; ks < 3; ks++)
        E = __builtin_amdgcn_mfma_f32_16x16x32_bf16(a_h[ks], b_hA[ks], E, 0, 0, 0);
      ushortT ev16[4];
#pragma unroll
      for (int r = 0; r < 4; r++) ev16[r] = f2h(E[r]);
      {
        const unsigned lo = (unsigned)ev16[0] | ((unsigned)ev16[1] << 16);
        const unsigned hi = (unsigned)ev16[2] | ((unsigned)ev16[3] << 16);
        *(uint2*)(Et + tb) = (uint2){lo, hi};
      }
      const ushortT uu[4] = {(ushortT)(araw.x & 0xFFFF), (ushortT)(araw.x >> 16),
                             (ushortT)(araw.y & 0xFFFF), (ushortT)(araw.y >> 16)};
#pragma unroll
      for (int r = 0; r < 4; r++) {
        Ev[iter * 4 + r] = h2f(ev16[r]);
        g1m |= ((uu[r] & 0xFFFEu) ? 1u : 0u) << (iter * 4 + r);
        g2m |= (unsigned)(uu[r] & 1u) << (iter * 4 + r);
      }
    }
    // chunk-local deferred stats (shared reference over gate1)
    float Mc = -3.0e38f;
#pragma unroll
    for (int k = 0; k < 16; k++)
      Mc = ((g1m >> k) & 1u) ? fmaxf(Mc, Ev[k]) : Mc;
    float S1c = 0.f, S2c = 0.f;
#pragma unroll
    for (int k = 0; k < 16; k++) {
      const float t = __expf(Ev[k] - Mc);
      S1c += ((g1m >> k) & 1u) ? t : 0.f;
      S2c += ((g2m >> k) & 1u) ? t : 0.f;
    }
    const float nM = fmaxf(Mrun, Mc);
    const float fa = __expf(Mrun - nM), fb = __expf(Mc - nM);
    S1run = S1run * fa + S1c * fb;
    S2run = S2run * fa + S2c * fb;
    Mrun = nM;
  }
#pragma unroll
  for (int off = 16; off <= 32; off <<= 1) {
    const float Mo = __shfl_xor(Mrun, off);
    const float S1o = __shfl_xor(S1run, off);
    const float S2o = __shfl_xor(S2run, off);
    const float nM = fmaxf(Mrun, Mo);
    const float fa = __expf(Mrun - nM), fb = __expf(Mo - nM);
    S1run = S1run * fa + S1o * fb;
    S2run = S2run * fa + S2o * fb;
    Mrun = nM;
  }
  __shared__ float sM[4][16], sS1[4][16], sS2[4][16];
  if (lane < 16) { sM[w][lr] = Mrun; sS1[w][lr] = S1run; sS2[w][lr] = S2run; }
  __syncthreads();
  if (tid < 32) {
    const int jhh = tid >> 4, l2 = tid & 15;
    const float Ma = sM[jhh][l2], Mb = sM[2 + jhh][l2];
    const float nM = fmaxf(Ma, Mb);
    const float fa = __expf(Ma - nM), fb = __expf(Mb - nM);
    const size_t o = ((size_t)b * 4 + ic) * N_ + j0 + jhh * 16 + l2;
    M1p[o] = nM;
    S1p[o] = sS1[jhh][l2] * fa + sS1[2 + jhh][l2] * fb;
    S2p[o] = sS2[jhh][l2] * fa + sS2[2 + jhh][l2] * fb;
  }
}

// --------------------- passPV: prefetched E/adj tiles, weights, PV MFMA
#define NJT 16
#define ICN 4
__global__ __launch_bounds__(256) void passPV_mfma(
    const ushortT* __restrict__ adj_t, const ushortT* __restrict__ Et,
    const short* __restrict__ hT16,
    const float* __restrict__ M1p, const float* __restrict__ S1p,
    const float* __restrict__ S2p,
    ushortT* __restrict__ hp1p, ushortT* __restrict__ hp2p)
{
  const int it = blockIdx.x, jc = blockIdx.y, b = blockIdx.z;
  const int tid = threadIdx.x, w = tid >> 6, lane = tid & 63;
  const int lr = lane & 15, kg = lane >> 4;
  const int ih = w >> 1, jh = w & 1;
  const int dbase = (w & 1) * 3;
  const int jbase = jc * NJT * 32;
  const int lofs = (jh * 16 + lr) * 32 + (ih * 16 + kg * 4);

  __shared__ float sMS[3][NJT * 32];
  for (int idx = tid; idx < NJT * 32; idx += 256) {
    const int col = jbase + idx;
    float Mv[ICN];
    float M = -3.0e38f;
#pragma unroll
    for (int q = 0; q < ICN; q++) {
      Mv[q] = M1p[((size_t)b * ICN + q) * N_ + col];
      M = fmaxf(M, Mv[q]);
    }
    float S1 = 0.f, S2 = 0.f;
#pragma unroll
    for (int q = 0; q < ICN; q++) {
      const float f = __expf(Mv[q] - M);
      S1 += S1p[((size_t)b * ICN + q) * N_ + col] * f;
      S2 += S2p[((size_t)b * ICN + q) * N_ + col] * f;
    }
    sMS[0][idx] = M; sMS[1][idx] = 1.0f / S1; sMS[2][idx] = 1.0f / S2;
  }

  const short* hTb = hT16 + (size_t)b * DK_ * N_;
  f32x4 acc[2][3];
#pragma unroll
  for (int m = 0; m < 2; m++)
#pragma unroll
    for (int q = 0; q < 3; q++) acc[m][q] = (f32x4){0.f, 0.f, 0.f, 0.f};

  __shared__ short wlds[2][2][32][40];
  __syncthreads();

  size_t tb = ((size_t)(b * 32 + jc * NJT) * 32 + it) * 1024 + lofs;
  uint2 eraw = *(const uint2*)(Et + tb);
  uint2 araw = *(const uint2*)(adj_t + tb);

#pragma unroll
  for (int t = 0; t < NJT; ++t) {
    const int j0 = jbase + t * 32;
    const int par = t & 1;
    bf16x8 bt[3];
#pragma unroll
    for (int q = 0; q < 3; q++)
      bt[q] = *(const bf16x8*)(hTb + (size_t)((dbase + q) * 16 + lr) * N_ + j0 + kg * 8);
    uint2 eN, aN;
    if (t + 1 < NJT) {
      const size_t tbn = ((size_t)(b * 32 + jc * NJT + t + 1) * 32 + it) * 1024 + lofs;
      eN = *(const uint2*)(Et + tbn);
      aN = *(const uint2*)(adj_t + tbn);
    }

    const ushortT ev[4] = {(ushortT)(eraw.x & 0xFFFF), (ushortT)(eraw.x >> 16),
                           (ushortT)(eraw.y & 0xFFFF), (ushortT)(eraw.y >> 16)};
    const ushortT uu[4] = {(ushortT)(araw.x & 0xFFFF), (ushortT)(araw.x >> 16),
                           (ushortT)(araw.y & 0xFFFF), (ushortT)(araw.y >> 16)};
    const int jrel = t * 32 + jh * 16 + lr;
    const float M1j = sMS[0][jrel], is1 = sMS[1][jrel], is2 = sMS[2][jrel];

    short w1v[4], w2v[4];
#pragma unroll
    for (int r = 0; r < 4; r++) {
      const float e = h2f(ev[r]);
      const float ex = __expf(e - M1j);          // shared for both masks
      const float adj1v = bfdec(uu[r] & 0xFFFEu);
      w1v[r] = f2bf((uu[r] & 0xFFFEu) ? ex * adj1v * is1 : 0.f);
      w2v[r] = f2bf((uu[r] & 1u) ? ex * is2 : 0.f);
    }
#pragma unroll
    for (int r = 0; r < 4; r++) {
      wlds[par][0][ih * 16 + kg * 4 + r][jh * 16 + lr] = w1v[r];
      wlds[par][1][ih * 16 + kg * 4 + r][jh * 16 + lr] = w2v[r];
    }
    __syncthreads();
#pragma unroll
    for (int m = 0; m < 2; m++) {
      bf16x8 af = *(const bf16x8*)&wlds[par][m][ih * 16 + lr][kg * 8];
#pragma unroll
      for (int q = 0; q < 3; q++)
        acc[m][q] = __builtin_amdgcn_mfma_f32_16x16x32_bf16(af, bt[q], acc[m][q], 0, 0, 0);
    }
    eraw = eN; araw = aN;
  }
  const int i0 = it * 32;
#pragma unroll
  for (int m = 0; m < 2; m++) {
#pragma unroll
    for (int q = 0; q < 3; q++) {
      const int dt = dbase + q;
      if (dt < 5) {
        ushortT* dst = (m ? hp2p : hp1p) +
            (((size_t)jc * B_ + b) * N_ + i0 + ih * 16 + kg * 4) * 80 + dt * 16 + lr;
#pragma unroll
        for (int r = 0; r < 4; r++) dst[(size_t)r * 80] = (ushortT)f2bf(acc[m][q][r]);
      }
    }
  }
}

// ------------- final-layer combine fused with masked pool (atomic into pooled)
__global__ __launch_bounds__(256) void combine_pool(
    const float* __restrict__ x,
    const ushortT* __restrict__ hp1p, const ushortT* __restrict__ hp2p, int JC,
    const float* __restrict__ g1, const float* __restrict__ g2w,
    const float* __restrict__ g2b,
    const float* __restrict__ V, float* __restrict__ pooled)
{
  const int r = blockIdx.x * 4 + (threadIdx.x >> 6);
  const int t = threadIdx.x & 63;
  __shared__ float sAcc[D_];
  if (threadIdx.x < D_) sAcc[threadIdx.x] = 0.f;
  __syncthreads();
  float s1a = 0.f, s2a = 0.f, s1b = 0.f, s2b = 0.f;
  for (int q = 0; q < JC; q++) {
    const size_t base = ((size_t)q * (B_ * N_) + r) * 80;
    s1a += bfdec(hp1p[base + t]);
    s2a += bfdec(hp2p[base + t]);
    if (t < D_ - 64) {
      s1b += bfdec(hp1p[base + 64 + t]);
      s2b += bfdec(hp2p[base + 64 + t]);
    }
  }
  const float a0 = fmaxf(s1a, 0.f), b0 = fmaxf(s2a, 0.f);
  const float a1v = fmaxf(s1b, 0.f), b1v = fmaxf(s2b, 0.f);
  const float* xr = x + (size_t)r * D_;
  const float x0 = xr[t];
  float d1 = x0 * g1[t], d2 = a0 * g2w[t], d3 = b0 * g2w[t];
  float x1 = 0.f;
  if (t < D_ - 64) {
    x1 = xr[64 + t];
    d1 += x1 * g1[64 + t]; d2 += a1v * g2w[64 + t]; d3 += b1v * g2w[64 + t];
  }
#pragma unroll
  for (int off = 1; off < 64; off <<= 1) {
    d1 += __shfl_xor(d1, off);
    d2 += __shfl_xor(d2, off);
    d3 += __shfl_xor(d3, off);
  }
  const float bb = g2b[0];
  const float c1 = 1.f / (1.f + __expf(-(d1 + d2 + bb)));
  const float c2 = 1.f / (1.f + __expf(-(d1 + d3 + bb)));
  const float Vr = V[r];
  const float o0 = (c1 * x0 + (1.f - c1) * a0) - (c2 * x0 + (1.f - c2) * b0);
  atomicAdd(&sAcc[t], o0 * Vr);
  if (t < D_ - 64) {
    const float o1 = (c1 * x1 + (1.f - c1) * a1v) - (c2 * x1 + (1.f - c2) * b1v);
    atomicAdd(&sAcc[64 + t], o1 * Vr);
  }
  __syncthreads();
  if (threadIdx.x < D_) {
    const int b = blockIdx.x >> 8;
    atomicAdd(&pooled[b * D_ + threadIdx.x], sAcc[threadIdx.x]);
  }
}

// ------------- MLP head: 8 blocks (one per batch row) x 1024 thr, 8-way sliced
__global__ __launch_bounds__(1024) void fc_kernel(
    const float* __restrict__ pooled,
    const float* __restrict__ w0, const float* __restrict__ b0,
    const float* __restrict__ w1, const float* __restrict__ b1,
    const float* __restrict__ w2, const float* __restrict__ b2,
    const float* __restrict__ w3, const float* __restrict__ b3,
    float* __restrict__ out)
{
  const int b = blockIdx.x;
  const int t = threadIdx.x;
  const int o = t >> 3, s = t & 7;
  __shared__ float pin[D_];
  __shared__ float part[DFC_][9];
  __shared__ float bufA[DFC_], bufB[DFC_];
  if (t < D_) pin[t] = pooled[b * D_ + t];
  __syncthreads();
  {
    float a = 0.f;
    const int m0 = s * 9, m1 = (m0 + 9 < D_) ? m0 + 9 : D_;
    for (int m = m0; m < m1; m++) a += pin[m] * w0[o * D_ + m];
    part[o][s] = a;
  }
  __syncthreads();
  if (t < DFC_) {
    float a = b0[t];
#pragma unroll
    for (int q = 0; q < 8; q++) a += part[t][q];
    bufA[t] = fmaxf(a, 0.f);
  }
  __syncthreads();
  {
    float a = 0.f;
    const float4* wr = (const float4*)(w1 + o * DFC_ + s * 16);
    const float4* br = (const float4*)&bufA[s * 16];
#pragma unroll
    for (int m4 = 0; m4 < 4; m4++) a += dot4(br[m4], wr[m4]);
    part[o][s] = a;
  }
  __syncthreads();
  if (t < DFC_) {
    float a = b1[t];
#pragma unroll
    for (int q = 0; q < 8; q++) a += part[t][q];
    bufB[t] = fmaxf(a, 0.f);
  }
  __syncthreads();
  {
    float a = 0.f;
    const float4* wr = (const float4*)(w2 + o * DFC_ + s * 16);
    const float4* br = (const float4*)&bufB[s * 16];
#pragma unroll
    for (int m4 = 0; m4 < 4; m4++) a += dot4(br[m4], wr[m4]);
    part[o][s] = a;
  }
  __syncthreads();
  if (t < DFC_) {
    float a = b2[t];
#pragma unroll
    for (int q = 0; q < 8; q++) a += part[t][q];
    bufA[t] = fmaxf(a, 0.f);
  }
  __syncthreads();
  if (t < 32) {
    const float4 wv = *(const float4*)(w3 + t * 4);
    const float4 bv = *(const float4*)&bufA[t * 4];
    float a = dot4(bv, wv);
    a += __shfl_xor(a, 1); a += __shfl_xor(a, 2); a += __shfl_xor(a, 4);
    a += __shfl_xor(a, 8); a += __shfl_xor(a, 16);
    if (t == 0) out[b] = 1.f / (1.f + __expf(-(a + b3[0])));
  }
}

// ----------------------------------------------------------------------
extern "C" void kernel_launch(void* const* d_in, const int* in_sizes, int n_in,
                              void* d_out, int out_size, void* d_ws, size_t ws_size,
                              hipStream_t stream)
{
  const float* H     = (const float*)d_in[0];
  const float* A1    = (const float*)d_in[1];
  const float* A2    = (const float*)d_in[2];
  const float* V     = (const float*)d_in[3];
  const float* few   = (const float*)d_in[4];
  const float* mup   = (const float*)d_in[5];
  const float* devp  = (const float*)d_in[6];
  const float* gW    = (const float*)d_in[7];
  const float* gA    = (const float*)d_in[8];
  const float* g1    = (const float*)d_in[9];
  const float* g2w   = (const float*)d_in[10];
  const float* g2b   = (const float*)d_in[11];
  const float* w0 = (const float*)d_in[12]; const float* b0 = (const float*)d_in[13];
  const float* w1 = (const float*)d_in[14]; const float* b1 = (const float*)d_in[15];
  const float* w2 = (const float*)d_in[16]; const float* b2 = (const float*)d_in[17];
  const float* w3 = (const float*)d_in[18]; const float* b3 = (const float*)d_in[19];
  float* outp = (float*)d_out;

  float* ws = (float*)d_ws;
  // fixed layout (float offsets)
  float*   x      = ws;                         // 573440
  short*   hb16   = (short*)(ws + 573440);
  short*   hAb16  = (short*)(ws + 966656);
  short*   hT16   = (short*)(ws + 1359872);
  short*   Wb16   = (short*)(ws + 1753088);
  short*   Atb16  = (short*)(ws + 1768448);
  short*   fewb16 = (short*)(ws + 1783808);     // 80*64 bf16 -> 1786368
  float*   M1p    = ws + 1786368;               // 4*B*N each (alloc 8*B*N spacing kept)
  float*   S1p    = ws + 1851904;
  float*   S2p    = ws + 1917440;
  float*   pooled = ws + 2048512;               // -> 2049088
  ushortT* adj_t  = (ushortT*)(ws + 2049088);   // 8M u16 -> 6243392
  ushortT* Et     = (ushortT*)(ws + 6243392);   // 8M u16 -> 10437696
  const int JC = 2;                              // = 32 / NJT
  ushortT* hp1p   = (ushortT*)(ws + 10437696);
  ushortT* hp2p   = hp1p + (size_t)JC * 655360u;
  const size_t need = (size_t)10437696u * 4u + (size_t)JC * 655360u * 4u;
  if (ws_size < need) return;
  const int ROWS = B_ * N_;

  prep_all<<<32 * 32 * B_ + 17, 256, 0, stream>>>(A1, A2, mup, devp, gW, gA, few,
      adj_t, Wb16, Atb16, fewb16, hT16, pooled);

  for (int k = 0; k < 4; k++) {
    const short* Wk  = Wb16  + (size_t)k * 80 * 96;
    const short* Atk = Atb16 + (size_t)k * 80 * 96;
    if (k == 0)
      gatmm_mfma<0><<<ROWS / GR, 128, 0, stream>>>(
          x, H, fewb16, nullptr, nullptr, 0, nullptr, nullptr, nullptr,
          Wk, Atk, hb16, hAb16, hT16);
    else
      gatmm_mfma<1><<<ROWS / GR, 128, 0, stream>>>(
          x, nullptr, nullptr, hp1p, hp2p, JC,
          g1 + (size_t)(k - 1) * D_, g2w + (size_t)(k - 1) * D_, g2b + (k - 1),
          Wk, Atk, hb16, hAb16, hT16);
    passE_mfma<<<dim3(32, ICN, B_), 256, 0, stream>>>(adj_t, hb16, hAb16, Et,
                                                      M1p, S1p, S2p);
    passPV_mfma<<<dim3(32, JC, B_), 256, 0, stream>>>(adj_t, Et, hT16,
        M1p, S1p, S2p, hp1p, hp2p);
  }
  combine_pool<<<ROWS / 4, 256, 0, stream>>>(x, hp1p, hp2p, JC,
      g1 + 3 * D_, g2w + 3 * D_, g2b + 3, V, pooled);
  fc_kernel<<<B_, 1024, 0, stream>>>(pooled, w0, b0, w1, b1, w2, b2, w3, b3, outp);
}